// Round 1
// baseline (3950.143 us; speedup 1.0000x reference)
//
#include <hip/hip_runtime.h>
#include <string.h>

#define BT_TOK 8192   // B*T
#define DDIM   2048
#define EEXP   8
#define HDIM   8192

typedef __bf16 bf16x8 __attribute__((ext_vector_type(8)));
typedef float  f32x4  __attribute__((ext_vector_type(4)));

__device__ inline ushort f2bf(float f) {
  unsigned u = __float_as_uint(f);
  u += 0x7FFFu + ((u >> 16) & 1u);   // RNE; inputs never NaN/Inf here
  return (ushort)(u >> 16);
}

__device__ inline void gl_lds16(const ushort* g, ushort* l) {
  __builtin_amdgcn_global_load_lds(
      (const __attribute__((address_space(1))) void*)g,
      (__attribute__((address_space(3))) void*)l, 16, 0, 0);
}

// ---------------- router: 1 wave per token ----------------
__global__ __launch_bounds__(256) void k_router(
    const float* __restrict__ x, const float* __restrict__ eps,
    const float* __restrict__ Wr, const float* __restrict__ br,
    const float* __restrict__ Wn, const float* __restrict__ bn,
    int* __restrict__ cnt, int* __restrict__ tk_e, int* __restrict__ tk_p,
    float* __restrict__ tk_g)
{
  const int lane = threadIdx.x & 63;
  const int t = blockIdx.x * 4 + (threadIdx.x >> 6);
  const float* xr = x + (size_t)t * DDIM;
  float aL[8] = {0,0,0,0,0,0,0,0};
  float aN[8] = {0,0,0,0,0,0,0,0};
  for (int i = lane; i < DDIM; i += 64) {
    float xv = xr[i];
    const float4* wr4 = (const float4*)(Wr + (size_t)i * EEXP);
    const float4* wn4 = (const float4*)(Wn + (size_t)i * EEXP);
    float4 r0 = wr4[0], r1 = wr4[1];
    float4 n0 = wn4[0], n1 = wn4[1];
    aL[0] += xv * r0.x; aL[1] += xv * r0.y; aL[2] += xv * r0.z; aL[3] += xv * r0.w;
    aL[4] += xv * r1.x; aL[5] += xv * r1.y; aL[6] += xv * r1.z; aL[7] += xv * r1.w;
    aN[0] += xv * n0.x; aN[1] += xv * n0.y; aN[2] += xv * n0.z; aN[3] += xv * n0.w;
    aN[4] += xv * n1.x; aN[5] += xv * n1.y; aN[6] += xv * n1.z; aN[7] += xv * n1.w;
  }
  #pragma unroll
  for (int e = 0; e < 8; ++e) {
    float v = aL[e];
    #pragma unroll
    for (int s = 32; s; s >>= 1) v += __shfl_xor(v, s);
    aL[e] = v;
    float w = aN[e];
    #pragma unroll
    for (int s = 32; s; s >>= 1) w += __shfl_xor(w, s);
    aN[e] = w;
  }
  float nz[8];
  #pragma unroll
  for (int e = 0; e < 8; ++e) {
    float l = aL[e] + br[e];
    float z = aN[e] + bn[e];
    float sp = fmaxf(z, 0.f) + log1pf(expf(-fabsf(z)));   // stable softplus
    nz[e] = l + eps[(size_t)t * EEXP + e] * sp;
  }
  // stable top-2 (ties -> lower index, matches jax.lax.top_k)
  int e1 = 0; float v1 = nz[0];
  #pragma unroll
  for (int e = 1; e < 8; ++e) if (nz[e] > v1) { v1 = nz[e]; e1 = e; }
  int e2 = (e1 == 0) ? 1 : 0; float v2 = nz[e2];
  #pragma unroll
  for (int e = 0; e < 8; ++e) if (e != e1 && nz[e] > v2) { v2 = nz[e]; e2 = e; }
  float ex = expf(v2 - v1);
  float g1 = 1.f / (1.f + ex);
  float g2 = ex / (1.f + ex);
  if (lane == 0) {
    int p1 = atomicAdd(&cnt[e1], 1);
    int p2 = atomicAdd(&cnt[e2], 1);
    tk_e[t * 2 + 0] = e1; tk_p[t * 2 + 0] = p1; tk_g[t * 2 + 0] = g1;
    tk_e[t * 2 + 1] = e2; tk_p[t * 2 + 1] = p2; tk_g[t * 2 + 1] = g2;
  }
}

// ---------------- offsets (prefix over 8 experts) ----------------
__global__ void k_off(const int* __restrict__ cnt, int* __restrict__ off) {
  if (threadIdx.x == 0 && blockIdx.x == 0) {
    int a = 0;
    for (int e = 0; e < EEXP; ++e) { off[e] = a; a += cnt[e]; }
    off[EEXP] = a;
  }
}

// ---------------- slot fill + gather x -> bf16 xg ----------------
__global__ __launch_bounds__(256) void k_gather(
    const float* __restrict__ x, const int* __restrict__ off,
    const int* __restrict__ tk_e, const int* __restrict__ tk_p,
    const float* __restrict__ tk_g,
    int* __restrict__ tok, float* __restrict__ gate, ushort* __restrict__ xg)
{
  const int b = blockIdx.x;           // 0..16383  (t,k) pair
  const int t = b >> 1;
  const int e = tk_e[b];
  const int slot = off[e] + tk_p[b];
  if (threadIdx.x == 0) { tok[slot] = t; gate[slot] = tk_g[b]; }
  const float4* src = (const float4*)(x + (size_t)t * DDIM);
  ushort* dst = xg + (size_t)slot * DDIM;
  const int i = threadIdx.x;          // 256 threads x 8 elems = 2048
  float4 a = src[i * 2 + 0];
  float4 c = src[i * 2 + 1];
  union { ushort u[8]; uint4 q; } pk;
  pk.u[0] = f2bf(a.x); pk.u[1] = f2bf(a.y); pk.u[2] = f2bf(a.z); pk.u[3] = f2bf(a.w);
  pk.u[4] = f2bf(c.x); pk.u[5] = f2bf(c.y); pk.u[6] = f2bf(c.z); pk.u[7] = f2bf(c.w);
  *(uint4*)(dst + (size_t)i * 8) = pk.q;
}

// ---------------- transpose + fp32->bf16:  W[e][R][C] -> Wt[e][C][R] ----------------
__global__ __launch_bounds__(256) void k_transpose(
    const float* __restrict__ W, ushort* __restrict__ Wt, int R, int C)
{
  const int e = blockIdx.z;
  const float* We = W + (size_t)e * R * C;
  ushort* Wte = Wt + (size_t)e * R * C;
  const int r0 = blockIdx.y * 64, c0 = blockIdx.x * 64;
  __shared__ float tile[64][65];
  const int tx = threadIdx.x & 15, ty = threadIdx.x >> 4;
  #pragma unroll
  for (int p = 0; p < 4; ++p) {
    float4 v = *(const float4*)(We + (size_t)(r0 + p * 16 + ty) * C + c0 + tx * 4);
    tile[p * 16 + ty][tx * 4 + 0] = v.x;
    tile[p * 16 + ty][tx * 4 + 1] = v.y;
    tile[p * 16 + ty][tx * 4 + 2] = v.z;
    tile[p * 16 + ty][tx * 4 + 3] = v.w;
  }
  __syncthreads();
  const int c = threadIdx.x >> 2, rb = (threadIdx.x & 3) * 16;
  union { ushort u[16]; uint4 q[2]; } pk;
  #pragma unroll
  for (int j = 0; j < 16; ++j) pk.u[j] = f2bf(tile[rb + j][c]);
  uint4* dst = (uint4*)(Wte + (size_t)(c0 + c) * R + r0 + rb);
  dst[0] = pk.q[0];
  dst[1] = pk.q[1];
}

// ---------------- grouped GEMM, m97 structure ----------------
// A: [slots][KD] bf16 (row-major).  B: [E][NDIM][KD] bf16 (pre-transposed = B^T).
// EPI=0: Hout[slot][NDIM] = bf16(relu(acc + bias[e][n]))
// EPI=1: atomicAdd(Out[tok[slot]][n], gate[slot]*(acc + bias[e][n]))
template<int KD, int EPI, int NDIM>
__global__ __launch_bounds__(256) void k_gemm(
    const ushort* __restrict__ A, const ushort* __restrict__ B,
    const float* __restrict__ bias, const int* __restrict__ off,
    const int* __restrict__ tok, const float* __restrict__ gate,
    ushort* __restrict__ Hout, float* __restrict__ Out)
{
  const int e = blockIdx.z;
  const int o = off[e];
  const int n_e = off[e + 1] - o;
  const int mi = blockIdx.x;
  if (mi * 128 >= n_e) return;
  const int ni = blockIdx.y;
  const int tid = threadIdx.x, lane = tid & 63, wid = tid >> 6;
  const int wr = (wid >> 1) * 64, wc = (wid & 1) * 64;
  __shared__ ushort As[128 * 64];
  __shared__ ushort Bs[128 * 64];

  const int colk = (tid & 7) * 8;   // k-offset of this thread's 16B chunk
  const int srow = tid >> 3;        // 0..31 staging row within a 32-row group
  const ushort* Bex = B + (size_t)e * NDIM * KD;
  const ushort* ag[4];
  const ushort* bg[4];
  #pragma unroll
  for (int i = 0; i < 4; ++i) {
    int r = i * 32 + srow;
    int ar = mi * 128 + r;
    if (ar > n_e - 1) ar = n_e - 1;            // clamp partial M-tile
    ag[i] = A + (size_t)(o + ar) * KD + colk;
    bg[i] = Bex + (size_t)(ni * 128 + r) * KD + colk;
  }

  f32x4 acc[4][4];
  #pragma unroll
  for (int m = 0; m < 4; ++m)
    #pragma unroll
    for (int n = 0; n < 4; ++n) acc[m][n] = (f32x4){0.f, 0.f, 0.f, 0.f};

  const int fr = lane & 15, fk = (lane >> 4) * 8;
  const ushort* ardL = &As[(wr + fr) * 64 + fk];
  const ushort* brdL = &Bs[(wc + fr) * 64 + fk];

  for (int k0 = 0; k0 < KD; k0 += 64) {
    __syncthreads();
    #pragma unroll
    for (int i = 0; i < 4; ++i) {
      gl_lds16(ag[i], &As[(i * 32 + srow) * 64 + colk]);
      gl_lds16(bg[i], &Bs[(i * 32 + srow) * 64 + colk]);
      ag[i] += 64; bg[i] += 64;
    }
    __syncthreads();
    #pragma unroll
    for (int kk = 0; kk < 64; kk += 32) {
      bf16x8 av[4], bv[4];
      #pragma unroll
      for (int m = 0; m < 4; ++m) av[m] = *(const bf16x8*)(ardL + m * 16 * 64 + kk);
      #pragma unroll
      for (int n = 0; n < 4; ++n) bv[n] = *(const bf16x8*)(brdL + n * 16 * 64 + kk);
      #pragma unroll
      for (int m = 0; m < 4; ++m)
        #pragma unroll
        for (int n = 0; n < 4; ++n)
          acc[m][n] = __builtin_amdgcn_mfma_f32_16x16x32_bf16(av[m], bv[n], acc[m][n], 0, 0, 0);
    }
  }

  const int colb = ni * 128 + wc + fr;
  float bv4[4];
  #pragma unroll
  for (int n = 0; n < 4; ++n) bv4[n] = bias[(size_t)e * NDIM + colb + n * 16];
  const int rbase = mi * 128 + wr + (lane >> 4) * 4;

  if constexpr (EPI == 0) {
    #pragma unroll
    for (int m = 0; m < 4; ++m)
      #pragma unroll
      for (int j = 0; j < 4; ++j) {
        int r = rbase + m * 16 + j;
        if (r < n_e) {
          ushort* hp = Hout + (size_t)(o + r) * NDIM + colb;
          #pragma unroll
          for (int n = 0; n < 4; ++n)
            hp[n * 16] = f2bf(fmaxf(acc[m][n][j] + bv4[n], 0.f));
        }
      }
  } else {
    #pragma unroll
    for (int m = 0; m < 4; ++m)
      #pragma unroll
      for (int j = 0; j < 4; ++j) {
        int r = rbase + m * 16 + j;
        if (r < n_e) {
          int t = tok[o + r];
          float g = gate[o + r];
          float* op = Out + (size_t)t * DDIM + colb;
          #pragma unroll
          for (int n = 0; n < 4; ++n)
            atomicAdd(op + n * 16, g * (acc[m][n][j] + bv4[n]));
        }
      }
  }
}

extern "C" void kernel_launch(void* const* d_in, const int* in_sizes, int n_in,
                              void* d_out, int out_size, void* d_ws, size_t ws_size,
                              hipStream_t stream) {
  const float* x   = (const float*)d_in[0];
  const float* eps = (const float*)d_in[1];
  const float* Wr  = (const float*)d_in[2];
  const float* br  = (const float*)d_in[3];
  const float* Wn  = (const float*)d_in[4];
  const float* bn  = (const float*)d_in[5];
  const float* W1  = (const float*)d_in[6];
  const float* b1  = (const float*)d_in[7];
  const float* W2  = (const float*)d_in[8];
  const float* b2  = (const float*)d_in[9];
  float* out = (float*)d_out;

  // workspace carve
  char* p = (char*)d_ws;
  size_t used = 0;
  auto alloc = [&](size_t bytes) -> void* {
    void* r = p + used;
    used += (bytes + 255) & ~(size_t)255;
    return r;
  };
  int*    cnt  = (int*)alloc(EEXP * 4);
  int*    off  = (int*)alloc((EEXP + 1) * 4);
  int*    tk_e = (int*)alloc(2 * BT_TOK * 4);
  int*    tk_p = (int*)alloc(2 * BT_TOK * 4);
  float*  tk_g = (float*)alloc(2 * BT_TOK * 4);
  int*    tok  = (int*)alloc(2 * BT_TOK * 4);
  float*  gate = (float*)alloc(2 * BT_TOK * 4);
  ushort* xg   = (ushort*)alloc((size_t)2 * BT_TOK * DDIM * 2);
  ushort* Wt1  = (ushort*)alloc((size_t)EEXP * HDIM * DDIM * 2);
  ushort* Wt2  = (ushort*)alloc((size_t)EEXP * HDIM * DDIM * 2);
  ushort* hbuf = (ushort*)alloc((size_t)2 * BT_TOK * HDIM * 2);
  if (used > ws_size) {
    // workspace too small: leave d_out poisoned so the failure is identifiable
    return;
  }

  hipMemsetAsync(d_out, 0, (size_t)out_size * 4, stream);
  hipMemsetAsync(cnt, 0, EEXP * 4, stream);

  k_router<<<BT_TOK / 4, 256, 0, stream>>>(x, eps, Wr, br, Wn, bn,
                                           cnt, tk_e, tk_p, tk_g);
  k_off<<<1, 64, 0, stream>>>(cnt, off);
  k_gather<<<2 * BT_TOK, 256, 0, stream>>>(x, off, tk_e, tk_p, tk_g, tok, gate, xg);

  {
    dim3 g1(HDIM / 64, DDIM / 64, EEXP);   // W1 [D][H] -> Wt1 [H][D]
    k_transpose<<<g1, 256, 0, stream>>>(W1, Wt1, DDIM, HDIM);
    dim3 g2(DDIM / 64, HDIM / 64, EEXP);   // W2 [H][D] -> Wt2 [D][H]
    k_transpose<<<g2, 256, 0, stream>>>(W2, Wt2, HDIM, DDIM);
  }

  {
    dim3 gg1(64, HDIM / 128, EEXP);        // (Mtiles_max, Ntiles, E)
    k_gemm<DDIM, 0, HDIM><<<gg1, 256, 0, stream>>>(xg, Wt1, b1, off, tok, gate,
                                                   hbuf, out);
    dim3 gg2(64, DDIM / 128, EEXP);
    k_gemm<HDIM, 1, DDIM><<<gg2, 256, 0, stream>>>(hbuf, Wt2, b2, off, tok, gate,
                                                   hbuf, out);
  }
}

// Round 2
// 2002.023 us; speedup vs baseline: 1.9731x; 1.9731x over previous
//
#include <hip/hip_runtime.h>

#define BT_TOK 8192   // B*T
#define DDIM   2048
#define EEXP   8
#define HDIM   8192
#define MAXTILES 72   // sum_e ceil(n_e/256) <= 16384/256 + 8 = 72

typedef __bf16 bf16x8 __attribute__((ext_vector_type(8)));
typedef float  f32x4  __attribute__((ext_vector_type(4)));

__device__ inline ushort f2bf(float f) {
  unsigned u = __float_as_uint(f);
  u += 0x7FFFu + ((u >> 16) & 1u);   // RNE
  return (ushort)(u >> 16);
}

__device__ __forceinline__ void gl16(const ushort* g, ushort* l) {
  __builtin_amdgcn_global_load_lds(
      (const __attribute__((address_space(1))) void*)g,
      (__attribute__((address_space(3))) void*)l, 16, 0, 0);
}

// ---------------- router: 1 wave per token ----------------
__global__ __launch_bounds__(256) void k_router(
    const float* __restrict__ x, const float* __restrict__ eps,
    const float* __restrict__ Wr, const float* __restrict__ br,
    const float* __restrict__ Wn, const float* __restrict__ bn,
    int* __restrict__ cnt, int* __restrict__ tk_e, int* __restrict__ tk_p,
    float* __restrict__ tk_g)
{
  const int lane = threadIdx.x & 63;
  const int t = blockIdx.x * 4 + (threadIdx.x >> 6);
  const float* xr = x + (size_t)t * DDIM;
  float aL[8] = {0,0,0,0,0,0,0,0};
  float aN[8] = {0,0,0,0,0,0,0,0};
  for (int i = lane; i < DDIM; i += 64) {
    float xv = xr[i];
    const float4* wr4 = (const float4*)(Wr + (size_t)i * EEXP);
    const float4* wn4 = (const float4*)(Wn + (size_t)i * EEXP);
    float4 r0 = wr4[0], r1 = wr4[1];
    float4 n0 = wn4[0], n1 = wn4[1];
    aL[0] += xv * r0.x; aL[1] += xv * r0.y; aL[2] += xv * r0.z; aL[3] += xv * r0.w;
    aL[4] += xv * r1.x; aL[5] += xv * r1.y; aL[6] += xv * r1.z; aL[7] += xv * r1.w;
    aN[0] += xv * n0.x; aN[1] += xv * n0.y; aN[2] += xv * n0.z; aN[3] += xv * n0.w;
    aN[4] += xv * n1.x; aN[5] += xv * n1.y; aN[6] += xv * n1.z; aN[7] += xv * n1.w;
  }
  #pragma unroll
  for (int e = 0; e < 8; ++e) {
    float v = aL[e];
    #pragma unroll
    for (int s = 32; s; s >>= 1) v += __shfl_xor(v, s);
    aL[e] = v;
    float w = aN[e];
    #pragma unroll
    for (int s = 32; s; s >>= 1) w += __shfl_xor(w, s);
    aN[e] = w;
  }
  float nz[8];
  #pragma unroll
  for (int e = 0; e < 8; ++e) {
    float l = aL[e] + br[e];
    float z = aN[e] + bn[e];
    float sp = fmaxf(z, 0.f) + log1pf(expf(-fabsf(z)));   // stable softplus
    nz[e] = l + eps[(size_t)t * EEXP + e] * sp;
  }
  int e1 = 0; float v1 = nz[0];
  #pragma unroll
  for (int e = 1; e < 8; ++e) if (nz[e] > v1) { v1 = nz[e]; e1 = e; }
  int e2 = (e1 == 0) ? 1 : 0; float v2 = nz[e2];
  #pragma unroll
  for (int e = 0; e < 8; ++e) if (e != e1 && nz[e] > v2) { v2 = nz[e]; e2 = e; }
  float ex = expf(v2 - v1);
  float g1 = 1.f / (1.f + ex);
  float g2 = ex / (1.f + ex);
  if (lane == 0) {
    int p1 = atomicAdd(&cnt[e1], 1);
    int p2 = atomicAdd(&cnt[e2], 1);
    tk_e[t * 2 + 0] = e1; tk_p[t * 2 + 0] = p1; tk_g[t * 2 + 0] = g1;
    tk_e[t * 2 + 1] = e2; tk_p[t * 2 + 1] = p2; tk_g[t * 2 + 1] = g2;
  }
}

// ---------------- offsets + 256-row tile map ----------------
__global__ void k_off(const int* __restrict__ cnt, int* __restrict__ off,
                      int* __restrict__ tileMap, int* __restrict__ nTiles) {
  if (threadIdx.x == 0 && blockIdx.x == 0) {
    int a = 0, nt = 0;
    for (int e = 0; e < EEXP; ++e) {
      off[e] = a;
      int mt = (cnt[e] + 255) >> 8;
      for (int m = 0; m < mt; ++m) tileMap[nt++] = (e << 16) | m;
      a += cnt[e];
    }
    off[EEXP] = a;
    nTiles[0] = nt;
  }
}

// ---------------- slot fill + gather x -> bf16 xg ----------------
__global__ __launch_bounds__(256) void k_gather(
    const float* __restrict__ x, const int* __restrict__ off,
    const int* __restrict__ tk_e, const int* __restrict__ tk_p,
    const float* __restrict__ tk_g,
    int* __restrict__ tok, float* __restrict__ gate, ushort* __restrict__ xg)
{
  const int b = blockIdx.x;           // (t,k) pair
  const int t = b >> 1;
  const int e = tk_e[b];
  const int slot = off[e] + tk_p[b];
  if (threadIdx.x == 0) { tok[slot] = t; gate[slot] = tk_g[b]; }
  const float4* src = (const float4*)(x + (size_t)t * DDIM);
  ushort* dst = xg + (size_t)slot * DDIM;
  const int i = threadIdx.x;
  float4 a = src[i * 2 + 0];
  float4 c = src[i * 2 + 1];
  union { ushort u[8]; uint4 q; } pk;
  pk.u[0] = f2bf(a.x); pk.u[1] = f2bf(a.y); pk.u[2] = f2bf(a.z); pk.u[3] = f2bf(a.w);
  pk.u[4] = f2bf(c.x); pk.u[5] = f2bf(c.y); pk.u[6] = f2bf(c.z); pk.u[7] = f2bf(c.w);
  *(uint4*)(dst + (size_t)i * 8) = pk.q;
}

// ---------------- transpose + fp32->bf16:  W[e][R][C] -> Wt[e][C][R] ----------------
__global__ __launch_bounds__(256) void k_transpose(
    const float* __restrict__ W, ushort* __restrict__ Wt, int R, int C)
{
  const int e = blockIdx.z;
  const float* We = W + (size_t)e * R * C;
  ushort* Wte = Wt + (size_t)e * R * C;
  const int r0 = blockIdx.y * 64, c0 = blockIdx.x * 64;
  __shared__ float tile[64][65];
  const int tx = threadIdx.x & 15, ty = threadIdx.x >> 4;
  #pragma unroll
  for (int p = 0; p < 4; ++p) {
    float4 v = *(const float4*)(We + (size_t)(r0 + p * 16 + ty) * C + c0 + tx * 4);
    tile[p * 16 + ty][tx * 4 + 0] = v.x;
    tile[p * 16 + ty][tx * 4 + 1] = v.y;
    tile[p * 16 + ty][tx * 4 + 2] = v.z;
    tile[p * 16 + ty][tx * 4 + 3] = v.w;
  }
  __syncthreads();
  const int c = threadIdx.x >> 2, rb = (threadIdx.x & 3) * 16;
  union { ushort u[16]; uint4 q[2]; } pk;
  #pragma unroll
  for (int j = 0; j < 16; ++j) pk.u[j] = f2bf(tile[rb + j][c]);
  uint4* dst = (uint4*)(Wte + (size_t)(c0 + c) * R + r0 + rb);
  dst[0] = pk.q[0];
  dst[1] = pk.q[1];
}

// ---------------- grouped GEMM: 256x256 tile, BK=64, 8 waves, 8-phase ----------------
// A: [slots][KD] bf16.  B: [E][NDIM][KD] bf16 (pre-transposed).
// Wave w owns C rows [0,256) x cols [w*32, w*32+32). acc[16][2] f32x4.
// LDS: 2 buffers x (A 32KB + B 32KB) = 128KB. XOR swizzle: phys16Bchunk = logical ^ (row&7).
// Stage regions per K-tile: Ah0(rows0-127), Ah1(rows128-255), Bh0, Bh1; each 2 gl16/thread.
// Schedule per K-tile t (buf = t&1): P0 stages Ah1(t+1)->buf^1; P1 stages Bh01(t+2)->buf;
// P2 stages Ah0(t+2)->buf; P3 boundary: vmcnt(6) + barrier.  (Region safety: Ah1(t) read
// P2/P3; Bh(t) read P0; Ah0(t) read P0/P1 -- each overwritten only after its last read.)

#define MFMA_(a, b, c) __builtin_amdgcn_mfma_f32_16x16x32_bf16(a, b, c, 0, 0, 0)
#define DSR(D, A) asm volatile("ds_read_b128 %0, %1" : "=v"(D) : "v"(A))

#define MQUAD(M, AK0, AK1)                              \
    acc[M][0] = MFMA_(AK0, bv00, acc[M][0]);            \
    acc[M][0] = MFMA_(AK1, bv01, acc[M][0]);            \
    acc[M][1] = MFMA_(AK0, bv10, acc[M][1]);            \
    acc[M][1] = MFMA_(AK1, bv11, acc[M][1]);

#define PHASE(P, ...) do {                                                  \
    bf16x8 av0k0, av0k1, av1k0, av1k1, av2k0, av2k1, av3k0, av3k1;          \
    const int aph = aA + (P) * 8192;                                        \
    DSR(av0k0, aph);        DSR(av0k1, aph ^ 64);                           \
    DSR(av1k0, aph + 2048); DSR(av1k1, (aph + 2048) ^ 64);                  \
    DSR(av2k0, aph + 4096); DSR(av2k1, (aph + 4096) ^ 64);                  \
    DSR(av3k0, aph + 6144); DSR(av3k1, (aph + 6144) ^ 64);                  \
    if ((P) == 0) {                                                         \
      DSR(bv00, bB);        DSR(bv01, bB ^ 64);                             \
      DSR(bv10, bB + 2048); DSR(bv11, (bB + 2048) ^ 64);                    \
    }                                                                       \
    __VA_ARGS__;                                                            \
    __builtin_amdgcn_s_barrier();                                           \
    asm volatile("s_waitcnt lgkmcnt(0)");                                   \
    __builtin_amdgcn_sched_barrier(0);                                      \
    __builtin_amdgcn_s_setprio(1);                                          \
    MQUAD((P)*4 + 0, av0k0, av0k1)                                          \
    MQUAD((P)*4 + 1, av1k0, av1k1)                                          \
    MQUAD((P)*4 + 2, av2k0, av2k1)                                          \
    MQUAD((P)*4 + 3, av3k0, av3k1)                                          \
    __builtin_amdgcn_s_setprio(0);                                          \
  } while (0)

template<int KD, int EPI, int NDIM>
__global__ __launch_bounds__(512, 2) void k_gemm(
    const ushort* __restrict__ A, const ushort* __restrict__ B,
    const float* __restrict__ bias, const int* __restrict__ off,
    const int* __restrict__ tileMap, const int* __restrict__ nTiles,
    const int* __restrict__ tok, const float* __restrict__ gate,
    ushort* __restrict__ Hout, float* __restrict__ Out)
{
  constexpr int NKT = KD / 64;
  __shared__ ushort lds[65536];            // 128 KB
  const int bx = blockIdx.x;
  if (bx >= nTiles[0]) return;
  const int em = tileMap[bx];
  const int e = em >> 16, mi = em & 0xffff;
  const int o = off[e], n_e = off[e + 1] - o;
  const int ni = blockIdx.y;
  const int m0 = mi * 256;
  const int tid = threadIdx.x;
  const int lane = tid & 63, wid = tid >> 6;
  const int fr = lane & 15, q = lane >> 4;
  const int wc = wid * 32;

  // ---- staging source pointers (pre-swizzled global k-chunk) ----
  const ushort* Bex = B + (size_t)e * NDIM * KD;
  const int trow = tid >> 3;                       // 0..63
  const int kxor = ((tid & 7) ^ (trow & 7)) * 8;   // element offset of 16B chunk
  const ushort* aS[4]; const ushort* bS[4];
  #pragma unroll
  for (int hj = 0; hj < 4; ++hj) {
    int tr = (hj >> 1) * 128 + (hj & 1) * 64 + trow;
    int ar = m0 + tr; if (ar > n_e - 1) ar = n_e - 1;   // clamp partial M tile
    aS[hj] = A + (size_t)(o + ar) * KD + kxor;
    bS[hj] = Bex + (size_t)((size_t)ni * 256 + tr) * KD + kxor;
  }
  const int dstA = tid * 8;   // ushort index within region
#define STG(SRC, DUS) gl16((SRC), &lds[DUS])

  // ---- ds_read byte addresses (swizzled) ----
  const unsigned lbase =
      (unsigned)(size_t)(__attribute__((address_space(3))) ushort*)lds;
  const int swzB = (q ^ (fr & 7)) * 16;                 // byte offset of 16B chunk, kk=0
  const int aoffB = (int)lbase + fr * 128 + swzB;                 // + m*2048 (+^64 for kk=1)
  const int boffB = (int)lbase + 32768 + (wc + fr) * 128 + swzB;  // + n*2048

  f32x4 acc[16][2];
  #pragma unroll
  for (int m = 0; m < 16; ++m) {
    acc[m][0] = (f32x4){0.f, 0.f, 0.f, 0.f};
    acc[m][1] = (f32x4){0.f, 0.f, 0.f, 0.f};
  }
  bf16x8 bv00, bv01, bv10, bv11;

  // ---- prologue: stage Kt0 (B,Ah0,Ah1) + Kt1 (B,Ah0) in steady-state order ----
  STG(bS[0], 16384 + dstA);
  STG(bS[1], 20480 + dstA);
  STG(bS[2], 24576 + dstA);
  STG(bS[3], 28672 + dstA);
  STG(aS[0], 0 + dstA);
  STG(aS[1], 4096 + dstA);
  STG(aS[2], 8192 + dstA);
  STG(aS[3], 12288 + dstA);
  if (NKT > 1) {
    STG(bS[0] + 64, 32768 + 16384 + dstA);
    STG(bS[1] + 64, 32768 + 20480 + dstA);
    STG(bS[2] + 64, 32768 + 24576 + dstA);
    STG(bS[3] + 64, 32768 + 28672 + dstA);
    STG(aS[0] + 64, 32768 + 0 + dstA);
    STG(aS[1] + 64, 32768 + 4096 + dstA);
  }
  if (NKT > 2) asm volatile("s_waitcnt vmcnt(6)");
  else         asm volatile("s_waitcnt vmcnt(0)");
  __builtin_amdgcn_s_barrier();
  __builtin_amdgcn_sched_barrier(0);

  // ---- main loop: 4 phases per K-tile ----
  #pragma unroll 1
  for (int t = 0; t < NKT; ++t) {
    const int bbB = (t & 1) << 16;        // byte offset of current buffer
    const int aA = aoffB + bbB;
    const int bB = boffB + bbB;
    const int cbu = (t & 1) * 32768;      // ushort base, current buffer
    const int nbu = cbu ^ 32768;          // ushort base, next buffer

    PHASE(0,
      if (t + 1 < NKT) {
        STG(aS[2] + (size_t)(t + 1) * 64, nbu + 8192 + dstA);
        STG(aS[3] + (size_t)(t + 1) * 64, nbu + 12288 + dstA);
      }
    );
    __builtin_amdgcn_s_barrier();
    PHASE(1,
      if (t + 2 < NKT) {
        STG(bS[0] + (size_t)(t + 2) * 64, cbu + 16384 + dstA);
        STG(bS[1] + (size_t)(t + 2) * 64, cbu + 20480 + dstA);
        STG(bS[2] + (size_t)(t + 2) * 64, cbu + 24576 + dstA);
        STG(bS[3] + (size_t)(t + 2) * 64, cbu + 28672 + dstA);
      }
    );
    __builtin_amdgcn_s_barrier();
    PHASE(2,
      if (t + 2 < NKT) {
        STG(aS[0] + (size_t)(t + 2) * 64, cbu + 0 + dstA);
        STG(aS[1] + (size_t)(t + 2) * 64, cbu + 4096 + dstA);
      }
    );
    __builtin_amdgcn_s_barrier();
    PHASE(3, );
    __builtin_amdgcn_sched_barrier(0);
    if (t >= NKT - 2) asm volatile("s_waitcnt vmcnt(0)");
    else              asm volatile("s_waitcnt vmcnt(6)");
    __builtin_amdgcn_s_barrier();
    __builtin_amdgcn_sched_barrier(0);
  }

  // ---- epilogue ----
  const int colBase = ni * 256 + wc + fr;   // + n*16
  const int rBase = m0 + q * 4;             // + m*16 + jj
  const float bb0 = bias[(size_t)e * NDIM + colBase];
  const float bb1 = bias[(size_t)e * NDIM + colBase + 16];

  if constexpr (EPI == 0) {
    #pragma unroll
    for (int m = 0; m < 16; ++m) {
      #pragma unroll
      for (int jj = 0; jj < 4; ++jj) {
        int r = rBase + m * 16 + jj;
        if (r < n_e) {
          ushort* hp = Hout + (size_t)(o + r) * NDIM + colBase;
          hp[0]  = f2bf(fmaxf(acc[m][0][jj] + bb0, 0.f));
          hp[16] = f2bf(fmaxf(acc[m][1][jj] + bb1, 0.f));
        }
      }
    }
  } else {
    #pragma unroll
    for (int m = 0; m < 16; ++m) {
      #pragma unroll
      for (int jj = 0; jj < 4; ++jj) {
        int r = rBase + m * 16 + jj;
        if (r < n_e) {
          int tt = tok[o + r];
          float g = gate[o + r];
          float* op = Out + (size_t)tt * NDIM + colBase;
          atomicAdd(op,      g * (acc[m][0][jj] + bb0));
          atomicAdd(op + 16, g * (acc[m][1][jj] + bb1));
        }
      }
    }
  }
#undef STG
}

extern "C" void kernel_launch(void* const* d_in, const int* in_sizes, int n_in,
                              void* d_out, int out_size, void* d_ws, size_t ws_size,
                              hipStream_t stream) {
  const float* x   = (const float*)d_in[0];
  const float* eps = (const float*)d_in[1];
  const float* Wr  = (const float*)d_in[2];
  const float* br  = (const float*)d_in[3];
  const float* Wn  = (const float*)d_in[4];
  const float* bn  = (const float*)d_in[5];
  const float* W1  = (const float*)d_in[6];
  const float* b1  = (const float*)d_in[7];
  const float* W2  = (const float*)d_in[8];
  const float* b2  = (const float*)d_in[9];
  float* out = (float*)d_out;

  char* p = (char*)d_ws;
  size_t used = 0;
  auto alloc = [&](size_t bytes) -> void* {
    void* r = p + used;
    used += (bytes + 255) & ~(size_t)255;
    return r;
  };
  int*    cnt   = (int*)alloc(EEXP * 4);
  int*    off   = (int*)alloc((EEXP + 1) * 4);
  int*    tmap  = (int*)alloc(MAXTILES * 4);
  int*    ntl   = (int*)alloc(4);
  int*    tk_e  = (int*)alloc(2 * BT_TOK * 4);
  int*    tk_p  = (int*)alloc(2 * BT_TOK * 4);
  float*  tk_g  = (float*)alloc(2 * BT_TOK * 4);
  int*    tok   = (int*)alloc(2 * BT_TOK * 4);
  float*  gate  = (float*)alloc(2 * BT_TOK * 4);
  ushort* xg    = (ushort*)alloc((size_t)2 * BT_TOK * DDIM * 2);
  ushort* Wt1   = (ushort*)alloc((size_t)EEXP * HDIM * DDIM * 2);
  ushort* Wt2   = (ushort*)alloc((size_t)EEXP * HDIM * DDIM * 2);
  ushort* hbuf  = (ushort*)alloc((size_t)2 * BT_TOK * HDIM * 2);
  if (used > ws_size) return;

  hipMemsetAsync(d_out, 0, (size_t)out_size * 4, stream);
  hipMemsetAsync(cnt, 0, EEXP * 4, stream);

  k_router<<<BT_TOK / 4, 256, 0, stream>>>(x, eps, Wr, br, Wn, bn,
                                           cnt, tk_e, tk_p, tk_g);
  k_off<<<1, 64, 0, stream>>>(cnt, off, tmap, ntl);
  k_gather<<<2 * BT_TOK, 256, 0, stream>>>(x, off, tk_e, tk_p, tk_g, tok, gate, xg);

  {
    dim3 g1(HDIM / 64, DDIM / 64, EEXP);   // W1 [D][H] -> Wt1 [H][D]
    k_transpose<<<g1, 256, 0, stream>>>(W1, Wt1, DDIM, HDIM);
    dim3 g2(DDIM / 64, HDIM / 64, EEXP);   // W2 [H][D] -> Wt2 [D][H]
    k_transpose<<<g2, 256, 0, stream>>>(W2, Wt2, HDIM, DDIM);
  }

  {
    dim3 gg1(MAXTILES, HDIM / 256, 1);
    k_gemm<DDIM, 0, HDIM><<<gg1, 512, 0, stream>>>(xg, Wt1, b1, off, tmap, ntl,
                                                   tok, gate, hbuf, out);
    dim3 gg2(MAXTILES, DDIM / 256, 1);
    k_gemm<HDIM, 1, DDIM><<<gg2, 512, 0, stream>>>(hbuf, Wt2, b2, off, tmap, ntl,
                                                   tok, gate, hbuf, out);
  }
}

// Round 3
// 1918.370 us; speedup vs baseline: 2.0591x; 1.0436x over previous
//
#include <hip/hip_runtime.h>

#define BT_TOK 8192   // B*T
#define DDIM   2048
#define EEXP   8
#define HDIM   8192
#define MAXTILES 72   // sum_e ceil(n_e/256) <= 16384/256 + 8 = 72

typedef __bf16 bf16x8 __attribute__((ext_vector_type(8)));
typedef float  f32x4  __attribute__((ext_vector_type(4)));

__device__ inline ushort f2bf(float f) {
  unsigned u = __float_as_uint(f);
  u += 0x7FFFu + ((u >> 16) & 1u);   // RNE
  return (ushort)(u >> 16);
}

__device__ __forceinline__ void gl16(const ushort* g, ushort* l) {
  __builtin_amdgcn_global_load_lds(
      (const __attribute__((address_space(1))) void*)g,
      (__attribute__((address_space(3))) void*)l, 16, 0, 0);
}

// ---------------- router: 1 wave per token ----------------
__global__ __launch_bounds__(256) void k_router(
    const float* __restrict__ x, const float* __restrict__ eps,
    const float* __restrict__ Wr, const float* __restrict__ br,
    const float* __restrict__ Wn, const float* __restrict__ bn,
    int* __restrict__ cnt, int* __restrict__ tk_e, int* __restrict__ tk_p,
    float* __restrict__ tk_g)
{
  const int lane = threadIdx.x & 63;
  const int t = blockIdx.x * 4 + (threadIdx.x >> 6);
  const float* xr = x + (size_t)t * DDIM;
  float aL[8] = {0,0,0,0,0,0,0,0};
  float aN[8] = {0,0,0,0,0,0,0,0};
  for (int i = lane; i < DDIM; i += 64) {
    float xv = xr[i];
    const float4* wr4 = (const float4*)(Wr + (size_t)i * EEXP);
    const float4* wn4 = (const float4*)(Wn + (size_t)i * EEXP);
    float4 r0 = wr4[0], r1 = wr4[1];
    float4 n0 = wn4[0], n1 = wn4[1];
    aL[0] += xv * r0.x; aL[1] += xv * r0.y; aL[2] += xv * r0.z; aL[3] += xv * r0.w;
    aL[4] += xv * r1.x; aL[5] += xv * r1.y; aL[6] += xv * r1.z; aL[7] += xv * r1.w;
    aN[0] += xv * n0.x; aN[1] += xv * n0.y; aN[2] += xv * n0.z; aN[3] += xv * n0.w;
    aN[4] += xv * n1.x; aN[5] += xv * n1.y; aN[6] += xv * n1.z; aN[7] += xv * n1.w;
  }
  #pragma unroll
  for (int e = 0; e < 8; ++e) {
    float v = aL[e];
    #pragma unroll
    for (int s = 32; s; s >>= 1) v += __shfl_xor(v, s);
    aL[e] = v;
    float w = aN[e];
    #pragma unroll
    for (int s = 32; s; s >>= 1) w += __shfl_xor(w, s);
    aN[e] = w;
  }
  float nz[8];
  #pragma unroll
  for (int e = 0; e < 8; ++e) {
    float l = aL[e] + br[e];
    float z = aN[e] + bn[e];
    float sp = fmaxf(z, 0.f) + log1pf(expf(-fabsf(z)));   // stable softplus
    nz[e] = l + eps[(size_t)t * EEXP + e] * sp;
  }
  int e1 = 0; float v1 = nz[0];
  #pragma unroll
  for (int e = 1; e < 8; ++e) if (nz[e] > v1) { v1 = nz[e]; e1 = e; }
  int e2 = (e1 == 0) ? 1 : 0; float v2 = nz[e2];
  #pragma unroll
  for (int e = 0; e < 8; ++e) if (e != e1 && nz[e] > v2) { v2 = nz[e]; e2 = e; }
  float ex = expf(v2 - v1);
  float g1 = 1.f / (1.f + ex);
  float g2 = ex / (1.f + ex);
  if (lane == 0) {
    int p1 = atomicAdd(&cnt[e1], 1);
    int p2 = atomicAdd(&cnt[e2], 1);
    tk_e[t * 2 + 0] = e1; tk_p[t * 2 + 0] = p1; tk_g[t * 2 + 0] = g1;
    tk_e[t * 2 + 1] = e2; tk_p[t * 2 + 1] = p2; tk_g[t * 2 + 1] = g2;
  }
}

// ---------------- offsets + 256-row tile map ----------------
__global__ void k_off(const int* __restrict__ cnt, int* __restrict__ off,
                      int* __restrict__ tileMap, int* __restrict__ nTiles) {
  if (threadIdx.x == 0 && blockIdx.x == 0) {
    int a = 0, nt = 0;
    for (int e = 0; e < EEXP; ++e) {
      off[e] = a;
      int mt = (cnt[e] + 255) >> 8;
      for (int m = 0; m < mt; ++m) tileMap[nt++] = (e << 16) | m;
      a += cnt[e];
    }
    off[EEXP] = a;
    nTiles[0] = nt;
  }
}

// ---------------- slot fill + gather x -> bf16 xg ----------------
__global__ __launch_bounds__(256) void k_gather(
    const float* __restrict__ x, const int* __restrict__ off,
    const int* __restrict__ tk_e, const int* __restrict__ tk_p,
    const float* __restrict__ tk_g,
    int* __restrict__ tok, float* __restrict__ gate, ushort* __restrict__ xg)
{
  const int b = blockIdx.x;           // (t,k) pair
  const int t = b >> 1;
  const int e = tk_e[b];
  const int slot = off[e] + tk_p[b];
  if (threadIdx.x == 0) { tok[slot] = t; gate[slot] = tk_g[b]; }
  const float4* src = (const float4*)(x + (size_t)t * DDIM);
  ushort* dst = xg + (size_t)slot * DDIM;
  const int i = threadIdx.x;
  float4 a = src[i * 2 + 0];
  float4 c = src[i * 2 + 1];
  union { ushort u[8]; uint4 q; } pk;
  pk.u[0] = f2bf(a.x); pk.u[1] = f2bf(a.y); pk.u[2] = f2bf(a.z); pk.u[3] = f2bf(a.w);
  pk.u[4] = f2bf(c.x); pk.u[5] = f2bf(c.y); pk.u[6] = f2bf(c.z); pk.u[7] = f2bf(c.w);
  *(uint4*)(dst + (size_t)i * 8) = pk.q;
}

// ---------------- transpose + fp32->bf16:  W[e][R][C] -> Wt[e][C][R] ----------------
__global__ __launch_bounds__(256) void k_transpose(
    const float* __restrict__ W, ushort* __restrict__ Wt, int R, int C)
{
  const int e = blockIdx.z;
  const float* We = W + (size_t)e * R * C;
  ushort* Wte = Wt + (size_t)e * R * C;
  const int r0 = blockIdx.y * 64, c0 = blockIdx.x * 64;
  __shared__ float tile[64][65];
  const int tx = threadIdx.x & 15, ty = threadIdx.x >> 4;
  #pragma unroll
  for (int p = 0; p < 4; ++p) {
    float4 v = *(const float4*)(We + (size_t)(r0 + p * 16 + ty) * C + c0 + tx * 4);
    tile[p * 16 + ty][tx * 4 + 0] = v.x;
    tile[p * 16 + ty][tx * 4 + 1] = v.y;
    tile[p * 16 + ty][tx * 4 + 2] = v.z;
    tile[p * 16 + ty][tx * 4 + 3] = v.w;
  }
  __syncthreads();
  const int c = threadIdx.x >> 2, rb = (threadIdx.x & 3) * 16;
  union { ushort u[16]; uint4 q[2]; } pk;
  #pragma unroll
  for (int j = 0; j < 16; ++j) pk.u[j] = f2bf(tile[rb + j][c]);
  uint4* dst = (uint4*)(Wte + (size_t)(c0 + c) * R + r0 + rb);
  dst[0] = pk.q[0];
  dst[1] = pk.q[1];
}

// ---------------- grouped GEMM: 256x256 tile, BK=64, 8 waves (2Mx4N), persistent ----------------
// A: [slots][KD] bf16.  B: [E][NDIM][KD] bf16 (pre-transposed).
// Wave (wm,wn) owns rows [wm*128,+128) x cols [wn*64,+64); acc[8][4] f32x4 (AGPR).
// LDS: 2 buf x (A 32KB + B 32KB) = 128KB, XOR-swizzled (chunk ^= row&7).
// Phases per K-tile: P0 reads A[m0-3]+B[n0-1] (12), P1 A[m4-7] (8) + STG a0,a2(t+2),
// P2 B[n2-3] (4) + STG a1,a3(t+2), P3 STG b0-3(t+2); 16 MFMA each; vmcnt(8) at boundary.
// Region safety: A rows[0-63],[128-191] last read P0; rows[64-127],[192-255] P1; B P2.
// t+2 goes into the CURRENT buffer (same parity); t+1 was fully staged during t-1.

#define MFMA_(a, b, c) __builtin_amdgcn_mfma_f32_16x16x32_bf16(a, b, c, 0, 0, 0)
#define DSR(D, A) asm volatile("ds_read_b128 %0, %1" : "=v"(D) : "v"(A))

template<int KD, int EPI, int NDIM>
__global__ __launch_bounds__(512, 2) void k_gemm(
    const ushort* __restrict__ A, const ushort* __restrict__ B,
    const float* __restrict__ bias, const int* __restrict__ off,
    const int* __restrict__ tileMap, const int* __restrict__ nTiles,
    const int* __restrict__ tok, const float* __restrict__ gate,
    ushort* __restrict__ Hout, float* __restrict__ Out)
{
  constexpr int NKT = KD / 64;
  constexpr int NTN = NDIM / 256;
  __shared__ ushort lds[65536];            // 128 KB
  const int TM = nTiles[0];
  const int T = TM * NTN;

  // bijective XCD chunking over flat tile ids (n-major: f = ni*TM + mslot)
  const int bid = blockIdx.x;
  const int xcd = bid & 7, slot = bid >> 3;
  const int qq = T >> 3, rr = T & 7;
  const int base = xcd * qq + (xcd < rr ? xcd : rr);
  const int csz = qq + (xcd < rr ? 1 : 0);

  const int tid = threadIdx.x;
  const int lane = tid & 63, wid = tid >> 6;
  const int wm = wid >> 2, wn = wid & 3;
  const int fr = lane & 15, q2 = lane >> 4;
  const unsigned lbase =
      (unsigned)(size_t)(__attribute__((address_space(3))) ushort*)lds;
  const int swz = (q2 ^ (fr & 7)) * 16;
  const int aoff0 = (int)lbase + wm * 16384 + fr * 128 + swz;           // + mf*2048, ^64 kk=1
  const int boff0 = (int)lbase + 32768 + wn * 8192 + fr * 128 + swz;    // + nf*2048
  const int trow = tid >> 3;                         // 0..63
  const int kx = ((tid & 7) ^ (trow & 7)) * 8;       // pre-swizzled global k-chunk
  const int dstA = tid * 8;                          // ushort idx within region

#define STG(SRC, DUS) gl16((SRC), &lds[DUS])

  for (int it = slot; it < csz; it += 32) {
    const int f = base + it;
    const int ni = (int)((unsigned)f / (unsigned)TM);
    const int em = tileMap[f - ni * TM];
    const int e = em >> 16, mi = em & 0xffff;
    const int o = off[e], n_e = off[e + 1] - o;
    const int m0 = mi * 256;

    const ushort* Bex = B + (size_t)e * NDIM * KD + (size_t)ni * 256 * KD;
    const ushort* aS[4]; const ushort* bS[4];
    #pragma unroll
    for (int j = 0; j < 4; ++j) {
      int ar = m0 + j * 64 + trow;
      if (ar > n_e - 1) ar = n_e - 1;
      aS[j] = A + (size_t)(o + ar) * KD + kx;
      bS[j] = Bex + (size_t)(j * 64 + trow) * KD + kx;
    }

    f32x4 acc[8][4];
    #pragma unroll
    for (int m = 0; m < 8; ++m)
      #pragma unroll
      for (int n = 0; n < 4; ++n) acc[m][n] = (f32x4){0.f, 0.f, 0.f, 0.f};

    // ---- prologue: tile0 -> buf0, tile1 -> buf1 (issue order = consumer order) ----
    STG(aS[0], 0 + dstA);        STG(aS[2], 8192 + dstA);
    STG(aS[1], 4096 + dstA);     STG(aS[3], 12288 + dstA);
    STG(bS[0], 16384 + dstA);    STG(bS[1], 20480 + dstA);
    STG(bS[2], 24576 + dstA);    STG(bS[3], 28672 + dstA);
    if (NKT > 1) {
      STG(aS[0] + 64, 32768 + 0 + dstA);     STG(aS[2] + 64, 32768 + 8192 + dstA);
      STG(aS[1] + 64, 32768 + 4096 + dstA);  STG(aS[3] + 64, 32768 + 12288 + dstA);
      STG(bS[0] + 64, 32768 + 16384 + dstA); STG(bS[1] + 64, 32768 + 20480 + dstA);
      STG(bS[2] + 64, 32768 + 24576 + dstA); STG(bS[3] + 64, 32768 + 28672 + dstA);
      asm volatile("s_waitcnt vmcnt(8)");
    } else {
      asm volatile("s_waitcnt vmcnt(0)");
    }
    __builtin_amdgcn_s_barrier();
    __builtin_amdgcn_sched_barrier(0);

    #pragma unroll 1
    for (int t = 0; t < NKT; ++t) {
      const int bb = (t & 1) << 16;          // byte offset of current buffer
      const int aA = aoff0 + bb;
      const int bA = boff0 + bb;
      const int cbu = (t & 1) * 32768;       // ushort base of current buffer
      const size_t ko = (size_t)(t + 2) * 64;
      const bool pf = (t + 2 < NKT);

      bf16x8 avL[8], avH[8], bvL[4], bvH[4];

      // ---- P0: read A[m0-3] + B[n0-1], MFMA Q0 ----
      #pragma unroll
      for (int i = 0; i < 4; ++i) {
        DSR(avL[2 * i],     aA + i * 2048);
        DSR(avL[2 * i + 1], (aA + i * 2048) ^ 64);
      }
      DSR(bvL[0], bA);         DSR(bvL[1], bA ^ 64);
      DSR(bvL[2], bA + 2048);  DSR(bvL[3], (bA + 2048) ^ 64);
      __builtin_amdgcn_s_barrier();
      asm volatile("s_waitcnt lgkmcnt(0)");
      __builtin_amdgcn_sched_barrier(0);
      __builtin_amdgcn_s_setprio(1);
      #pragma unroll
      for (int i = 0; i < 4; ++i) {
        acc[i][0] = MFMA_(avL[2 * i], bvL[0], acc[i][0]);
        acc[i][0] = MFMA_(avL[2 * i + 1], bvL[1], acc[i][0]);
        acc[i][1] = MFMA_(avL[2 * i], bvL[2], acc[i][1]);
        acc[i][1] = MFMA_(avL[2 * i + 1], bvL[3], acc[i][1]);
      }
      __builtin_amdgcn_s_setprio(0);
      __builtin_amdgcn_s_barrier();

      // ---- P1: read A[m4-7], stage a0,a2(t+2), MFMA Q1 ----
      #pragma unroll
      for (int i = 0; i < 4; ++i) {
        DSR(avH[2 * i],     aA + 8192 + i * 2048);
        DSR(avH[2 * i + 1], (aA + 8192 + i * 2048) ^ 64);
      }
      if (pf) {
        STG(aS[0] + ko, cbu + 0 + dstA);
        STG(aS[2] + ko, cbu + 8192 + dstA);
      }
      __builtin_amdgcn_s_barrier();
      asm volatile("s_waitcnt lgkmcnt(0)");
      __builtin_amdgcn_sched_barrier(0);
      __builtin_amdgcn_s_setprio(1);
      #pragma unroll
      for (int i = 0; i < 4; ++i) {
        acc[4 + i][0] = MFMA_(avH[2 * i], bvL[0], acc[4 + i][0]);
        acc[4 + i][0] = MFMA_(avH[2 * i + 1], bvL[1], acc[4 + i][0]);
        acc[4 + i][1] = MFMA_(avH[2 * i], bvL[2], acc[4 + i][1]);
        acc[4 + i][1] = MFMA_(avH[2 * i + 1], bvL[3], acc[4 + i][1]);
      }
      __builtin_amdgcn_s_setprio(0);
      __builtin_amdgcn_s_barrier();

      // ---- P2: read B[n2-3], stage a1,a3(t+2), MFMA Q2 ----
      DSR(bvH[0], bA + 4096);  DSR(bvH[1], (bA + 4096) ^ 64);
      DSR(bvH[2], bA + 6144);  DSR(bvH[3], (bA + 6144) ^ 64);
      if (pf) {
        STG(aS[1] + ko, cbu + 4096 + dstA);
        STG(aS[3] + ko, cbu + 12288 + dstA);
      }
      __builtin_amdgcn_s_barrier();
      asm volatile("s_waitcnt lgkmcnt(0)");
      __builtin_amdgcn_sched_barrier(0);
      __builtin_amdgcn_s_setprio(1);
      #pragma unroll
      for (int i = 0; i < 4; ++i) {
        acc[i][2] = MFMA_(avL[2 * i], bvH[0], acc[i][2]);
        acc[i][2] = MFMA_(avL[2 * i + 1], bvH[1], acc[i][2]);
        acc[i][3] = MFMA_(avL[2 * i], bvH[2], acc[i][3]);
        acc[i][3] = MFMA_(avL[2 * i + 1], bvH[3], acc[i][3]);
      }
      __builtin_amdgcn_s_setprio(0);
      __builtin_amdgcn_s_barrier();

      // ---- P3: stage b0-3(t+2), MFMA Q3 (regs only), boundary vmcnt ----
      if (pf) {
        STG(bS[0] + ko, cbu + 16384 + dstA);
        STG(bS[1] + ko, cbu + 20480 + dstA);
        STG(bS[2] + ko, cbu + 24576 + dstA);
        STG(bS[3] + ko, cbu + 28672 + dstA);
      }
      __builtin_amdgcn_s_setprio(1);
      #pragma unroll
      for (int i = 0; i < 4; ++i) {
        acc[4 + i][2] = MFMA_(avH[2 * i], bvH[0], acc[4 + i][2]);
        acc[4 + i][2] = MFMA_(avH[2 * i + 1], bvH[1], acc[4 + i][2]);
        acc[4 + i][3] = MFMA_(avH[2 * i], bvH[2], acc[4 + i][3]);
        acc[4 + i][3] = MFMA_(avH[2 * i + 1], bvH[3], acc[4 + i][3]);
      }
      __builtin_amdgcn_s_setprio(0);
      __builtin_amdgcn_sched_barrier(0);
      if (t < NKT - 2) asm volatile("s_waitcnt vmcnt(8)");
      else             asm volatile("s_waitcnt vmcnt(0)");
      __builtin_amdgcn_s_barrier();
      __builtin_amdgcn_sched_barrier(0);
    }

    // ---- epilogue ----
    const int colBase = ni * 256 + wn * 64 + fr;      // + nf*16
    const int rBase = m0 + wm * 128 + q2 * 4;         // + mf*16 + jj
    float bb4[4];
    #pragma unroll
    for (int n = 0; n < 4; ++n) bb4[n] = bias[(size_t)e * NDIM + colBase + n * 16];

    if constexpr (EPI == 0) {
      #pragma unroll
      for (int m = 0; m < 8; ++m) {
        #pragma unroll
        for (int jj = 0; jj < 4; ++jj) {
          int r = rBase + m * 16 + jj;
          if (r < n_e) {
            ushort* hp = Hout + (size_t)(o + r) * NDIM + colBase;
            #pragma unroll
            for (int n = 0; n < 4; ++n)
              hp[n * 16] = f2bf(fmaxf(acc[m][n][jj] + bb4[n], 0.f));
          }
        }
      }
    } else {
      #pragma unroll
      for (int m = 0; m < 8; ++m) {
        #pragma unroll
        for (int jj = 0; jj < 4; ++jj) {
          int r = rBase + m * 16 + jj;
          if (r < n_e) {
            int tt = tok[o + r];
            float g = gate[o + r];
            float* op = Out + (size_t)tt * NDIM + colBase;
            #pragma unroll
            for (int n = 0; n < 4; ++n)
              atomicAdd(op + n * 16, g * (acc[m][n][jj] + bb4[n]));
          }
        }
      }
    }
  }
#undef STG
}

extern "C" void kernel_launch(void* const* d_in, const int* in_sizes, int n_in,
                              void* d_out, int out_size, void* d_ws, size_t ws_size,
                              hipStream_t stream) {
  const float* x   = (const float*)d_in[0];
  const float* eps = (const float*)d_in[1];
  const float* Wr  = (const float*)d_in[2];
  const float* br  = (const float*)d_in[3];
  const float* Wn  = (const float*)d_in[4];
  const float* bn  = (const float*)d_in[5];
  const float* W1  = (const float*)d_in[6];
  const float* b1  = (const float*)d_in[7];
  const float* W2  = (const float*)d_in[8];
  const float* b2  = (const float*)d_in[9];
  float* out = (float*)d_out;

  char* p = (char*)d_ws;
  size_t used = 0;
  auto alloc = [&](size_t bytes) -> void* {
    void* r = p + used;
    used += (bytes + 255) & ~(size_t)255;
    return r;
  };
  int*    cnt   = (int*)alloc(EEXP * 4);
  int*    off   = (int*)alloc((EEXP + 1) * 4);
  int*    tmap  = (int*)alloc(MAXTILES * 4);
  int*    ntl   = (int*)alloc(4);
  int*    tk_e  = (int*)alloc(2 * BT_TOK * 4);
  int*    tk_p  = (int*)alloc(2 * BT_TOK * 4);
  float*  tk_g  = (float*)alloc(2 * BT_TOK * 4);
  int*    tok   = (int*)alloc(2 * BT_TOK * 4);
  float*  gate  = (float*)alloc(2 * BT_TOK * 4);
  ushort* xg    = (ushort*)alloc((size_t)2 * BT_TOK * DDIM * 2);
  ushort* Wt1   = (ushort*)alloc((size_t)EEXP * HDIM * DDIM * 2);
  ushort* Wt2   = (ushort*)alloc((size_t)EEXP * HDIM * DDIM * 2);
  ushort* hbuf  = (ushort*)alloc((size_t)2 * BT_TOK * HDIM * 2);
  if (used > ws_size) return;

  hipMemsetAsync(d_out, 0, (size_t)out_size * 4, stream);
  hipMemsetAsync(cnt, 0, EEXP * 4, stream);

  k_router<<<BT_TOK / 4, 256, 0, stream>>>(x, eps, Wr, br, Wn, bn,
                                           cnt, tk_e, tk_p, tk_g);
  k_off<<<1, 64, 0, stream>>>(cnt, off, tmap, ntl);
  k_gather<<<2 * BT_TOK, 256, 0, stream>>>(x, off, tk_e, tk_p, tk_g, tok, gate, xg);

  {
    dim3 g1(HDIM / 64, DDIM / 64, EEXP);   // W1 [D][H] -> Wt1 [H][D]
    k_transpose<<<g1, 256, 0, stream>>>(W1, Wt1, DDIM, HDIM);
    dim3 g2(DDIM / 64, HDIM / 64, EEXP);   // W2 [H][D] -> Wt2 [D][H]
    k_transpose<<<g2, 256, 0, stream>>>(W2, Wt2, HDIM, DDIM);
  }

  {
    k_gemm<DDIM, 0, HDIM><<<256, 512, 0, stream>>>(xg, Wt1, b1, off, tmap, ntl,
                                                   tok, gate, hbuf, out);
    k_gemm<HDIM, 1, DDIM><<<256, 512, 0, stream>>>(hbuf, Wt2, b2, off, tmap, ntl,
                                                   tok, gate, hbuf, out);
  }
}

// Round 4
// 1793.737 us; speedup vs baseline: 2.2022x; 1.0695x over previous
//
#include <hip/hip_runtime.h>

#define BT_TOK 8192   // B*T
#define DDIM   2048
#define EEXP   8
#define HDIM   8192
#define MAXT1  72     // sum_e ceil(n_e/256) <= 64+8
#define MAXT2  144

typedef __bf16 bf16x8 __attribute__((ext_vector_type(8)));
typedef float  f32x4  __attribute__((ext_vector_type(4)));

__device__ inline ushort f2bf(float f) {
  unsigned u = __float_as_uint(f);
  u += 0x7FFFu + ((u >> 16) & 1u);   // RNE
  return (ushort)(u >> 16);
}

__device__ __forceinline__ void gl16(const ushort* g, ushort* l) {
  __builtin_amdgcn_global_load_lds(
      (const __attribute__((address_space(1))) void*)g,
      (__attribute__((address_space(3))) void*)l, 16, 0, 0);
}

// ---------------- router: 1 wave per token ----------------
__global__ __launch_bounds__(256) void k_router(
    const float* __restrict__ x, const float* __restrict__ eps,
    const float* __restrict__ Wr, const float* __restrict__ br,
    const float* __restrict__ Wn, const float* __restrict__ bn,
    int* __restrict__ cnt, int* __restrict__ tk_e, int* __restrict__ tk_p,
    float* __restrict__ tk_g)
{
  const int lane = threadIdx.x & 63;
  const int t = blockIdx.x * 4 + (threadIdx.x >> 6);
  const float* xr = x + (size_t)t * DDIM;
  float aL[8] = {0,0,0,0,0,0,0,0};
  float aN[8] = {0,0,0,0,0,0,0,0};
  for (int i = lane; i < DDIM; i += 64) {
    float xv = xr[i];
    const float4* wr4 = (const float4*)(Wr + (size_t)i * EEXP);
    const float4* wn4 = (const float4*)(Wn + (size_t)i * EEXP);
    float4 r0 = wr4[0], r1 = wr4[1];
    float4 n0 = wn4[0], n1 = wn4[1];
    aL[0] += xv * r0.x; aL[1] += xv * r0.y; aL[2] += xv * r0.z; aL[3] += xv * r0.w;
    aL[4] += xv * r1.x; aL[5] += xv * r1.y; aL[6] += xv * r1.z; aL[7] += xv * r1.w;
    aN[0] += xv * n0.x; aN[1] += xv * n0.y; aN[2] += xv * n0.z; aN[3] += xv * n0.w;
    aN[4] += xv * n1.x; aN[5] += xv * n1.y; aN[6] += xv * n1.z; aN[7] += xv * n1.w;
  }
  #pragma unroll
  for (int e = 0; e < 8; ++e) {
    float v = aL[e];
    #pragma unroll
    for (int s = 32; s; s >>= 1) v += __shfl_xor(v, s);
    aL[e] = v;
    float w = aN[e];
    #pragma unroll
    for (int s = 32; s; s >>= 1) w += __shfl_xor(w, s);
    aN[e] = w;
  }
  float nz[8];
  #pragma unroll
  for (int e = 0; e < 8; ++e) {
    float l = aL[e] + br[e];
    float z = aN[e] + bn[e];
    float sp = fmaxf(z, 0.f) + log1pf(expf(-fabsf(z)));   // stable softplus
    nz[e] = l + eps[(size_t)t * EEXP + e] * sp;
  }
  int e1 = 0; float v1 = nz[0];
  #pragma unroll
  for (int e = 1; e < 8; ++e) if (nz[e] > v1) { v1 = nz[e]; e1 = e; }
  int e2 = (e1 == 0) ? 1 : 0; float v2 = nz[e2];
  #pragma unroll
  for (int e = 0; e < 8; ++e) if (e != e1 && nz[e] > v2) { v2 = nz[e]; e2 = e; }
  float ex = expf(v2 - v1);
  float g1 = 1.f / (1.f + ex);
  float g2 = ex / (1.f + ex);
  if (lane == 0) {
    int p1 = atomicAdd(&cnt[e1], 1);
    int p2 = atomicAdd(&cnt[e2], 1);
    tk_e[t * 2 + 0] = e1; tk_p[t * 2 + 0] = p1; tk_g[t * 2 + 0] = g1;
    tk_e[t * 2 + 1] = e2; tk_p[t * 2 + 1] = p2; tk_g[t * 2 + 1] = g2;
  }
}

// ---------------- offsets + tile maps (pack = (e<<8)|(mi<<1)|kh) ----------------
__global__ void k_off(const int* __restrict__ cnt, int* __restrict__ off,
                      int* __restrict__ tm1, int* __restrict__ tm2,
                      int* __restrict__ ntl) {
  if (threadIdx.x == 0 && blockIdx.x == 0) {
    int a = 0, n1 = 0, n2 = 0;
    for (int e = 0; e < EEXP; ++e) {
      off[e] = a;
      int mt = (cnt[e] + 255) >> 8;
      for (int m = 0; m < mt; ++m) {
        tm1[n1++] = (e << 8) | (m << 1);
        tm2[n2++] = (e << 8) | (m << 1);
        tm2[n2++] = (e << 8) | (m << 1) | 1;
      }
      a += cnt[e];
    }
    off[EEXP] = a;
    ntl[0] = n1; ntl[1] = n2;
  }
}

// ---------------- slot fill + gather x -> bf16 xg ----------------
__global__ __launch_bounds__(256) void k_gather(
    const float* __restrict__ x, const int* __restrict__ off,
    const int* __restrict__ tk_e, const int* __restrict__ tk_p,
    const float* __restrict__ tk_g,
    int* __restrict__ slt, float* __restrict__ gate, ushort* __restrict__ xg)
{
  const int b = blockIdx.x;           // (t,k) pair
  const int t = b >> 1;
  const int e = tk_e[b];
  const int slot = off[e] + tk_p[b];
  if (threadIdx.x == 0) { slt[b] = slot; gate[slot] = tk_g[b]; }
  const float4* src = (const float4*)(x + (size_t)t * DDIM);
  ushort* dst = xg + (size_t)slot * DDIM;
  const int i = threadIdx.x;
  float4 a = src[i * 2 + 0];
  float4 c = src[i * 2 + 1];
  union { ushort u[8]; uint4 q; } pk;
  pk.u[0] = f2bf(a.x); pk.u[1] = f2bf(a.y); pk.u[2] = f2bf(a.z); pk.u[3] = f2bf(a.w);
  pk.u[4] = f2bf(c.x); pk.u[5] = f2bf(c.y); pk.u[6] = f2bf(c.z); pk.u[7] = f2bf(c.w);
  *(uint4*)(dst + (size_t)i * 8) = pk.q;
}

// ---------------- transpose + fp32->bf16:  W[e][R][C] -> Wt[e][C][R] ----------------
__global__ __launch_bounds__(256) void k_transpose(
    const float* __restrict__ W, ushort* __restrict__ Wt, int R, int C)
{
  const int e = blockIdx.z;
  const float* We = W + (size_t)e * R * C;
  ushort* Wte = Wt + (size_t)e * R * C;
  const int r0 = blockIdx.y * 64, c0 = blockIdx.x * 64;
  __shared__ float tile[64][65];
  const int tx = threadIdx.x & 15, ty = threadIdx.x >> 4;
  #pragma unroll
  for (int p = 0; p < 4; ++p) {
    float4 v = *(const float4*)(We + (size_t)(r0 + p * 16 + ty) * C + c0 + tx * 4);
    tile[p * 16 + ty][tx * 4 + 0] = v.x;
    tile[p * 16 + ty][tx * 4 + 1] = v.y;
    tile[p * 16 + ty][tx * 4 + 2] = v.z;
    tile[p * 16 + ty][tx * 4 + 3] = v.w;
  }
  __syncthreads();
  const int c = threadIdx.x >> 2, rb = (threadIdx.x & 3) * 16;
  union { ushort u[16]; uint4 q[2]; } pk;
  #pragma unroll
  for (int j = 0; j < 16; ++j) pk.u[j] = f2bf(tile[rb + j][c]);
  uint4* dst = (uint4*)(Wte + (size_t)(c0 + c) * R + r0 + rb);
  dst[0] = pk.q[0];
  dst[1] = pk.q[1];
}

// ---------------- grouped GEMM: 256x256 tile, BK=64, 8 waves (2Mx4N), persistent ----------------
// Read-ahead schedule: fragments ds_read one phase before use; counted lgkmcnt waits.
//   Q3(t-1): read avL(t),bvL(t)       Q0(t): read avH(t),  wait lgkm(8),  MFMA mLxnL, stage A-low(t+2)
//   Q1(t): read bvH(t), wait lgkm(4), MFMA mHxnL, stage A-high(t+2)
//   Q2(t):              wait lgkm(0), MFMA mLxnH, stage B(t+2)
//   Q3(t): vmcnt(8)+barrier, read avL/bvL(t+1), MFMA mHxnH (no wait)
// Staging is 2 K-tiles ahead into the CURRENT buffer (regions overwritten only after
// their last read completed, enforced by the counted waits + barrier lockstep).

#define MFMA_(a, b, c) __builtin_amdgcn_mfma_f32_16x16x32_bf16(a, b, c, 0, 0, 0)
#define DSR(D, A) asm volatile("ds_read_b128 %0, %1" : "=v"(D) : "v"(A))
#define MQ(MB, NB, AV, BV) do {                                                  \
    _Pragma("unroll")                                                            \
    for (int i_ = 0; i_ < 4; ++i_) {                                             \
      acc[(MB)+i_][(NB)]   = MFMA_(AV[2*i_],   BV[0], acc[(MB)+i_][(NB)]);       \
      acc[(MB)+i_][(NB)]   = MFMA_(AV[2*i_+1], BV[1], acc[(MB)+i_][(NB)]);       \
      acc[(MB)+i_][(NB)+1] = MFMA_(AV[2*i_],   BV[2], acc[(MB)+i_][(NB)+1]);     \
      acc[(MB)+i_][(NB)+1] = MFMA_(AV[2*i_+1], BV[3], acc[(MB)+i_][(NB)+1]);     \
    }                                                                            \
  } while (0)

template<int KD, int KSPLIT, int EPI, int NDIM>
__global__ __launch_bounds__(512, 2) void k_gemm(
    const ushort* __restrict__ A, const ushort* __restrict__ B,
    const float* __restrict__ bias, const int* __restrict__ off,
    const int* __restrict__ tileMap, const int* __restrict__ nT,
    const float* __restrict__ gate,
    ushort* __restrict__ Hout, float* __restrict__ Y)
{
  constexpr int KS = KD / KSPLIT;
  constexpr int NKT = KS / 64;
  constexpr int NTN = NDIM / 256;
  __shared__ ushort lds[65536];            // 128 KB
  const int TM = nT[0];
  const int T = TM * NTN;

  // bijective XCD chunking over flat tile ids (n-major: f = ni*TM + j)
  const int bid = blockIdx.x;
  const int xcd = bid & 7, sl = bid >> 3;
  const int qq = T >> 3, rr = T & 7;
  const int base = xcd * qq + (xcd < rr ? xcd : rr);
  const int csz = qq + (xcd < rr ? 1 : 0);

  const int tid = threadIdx.x;
  const int lane = tid & 63, wid = tid >> 6;
  const int wm = wid >> 2, wn = wid & 3;
  const int fr = lane & 15, q2 = lane >> 4;
  const unsigned lbase =
      (unsigned)(size_t)(__attribute__((address_space(3))) ushort*)lds;
  const int swz = (q2 ^ (fr & 7)) * 16;
  const int aoff0 = (int)lbase + wm * 16384 + fr * 128 + swz;           // + mf*2048, ^64 kk=1
  const int boff0 = (int)lbase + 32768 + wn * 8192 + fr * 128 + swz;    // + nf*2048
  const int trow = tid >> 3;                         // 0..63
  const int kx = ((tid & 7) ^ (trow & 7)) * 8;       // pre-swizzled global k-chunk
  const int dstA = tid * 8;                          // ushort idx within region

#define STG(SRC, DUS) gl16((SRC), &lds[DUS])

  for (int it = sl; it < csz; it += 32) {
    const int f = base + it;
    const int ni = (int)((unsigned)f / (unsigned)TM);
    const int pk = tileMap[f - ni * TM];
    const int e = pk >> 8, mi = (pk >> 1) & 127, kh = pk & 1;
    const int o = off[e], n_e = off[e + 1] - o;
    const int m0 = mi * 256;
    const int k0 = kh * KS;

    const ushort* Bex = B + (size_t)e * NDIM * KD + (size_t)ni * 256 * KD + k0 + kx;
    const ushort* aS[4]; const ushort* bS[4];
    #pragma unroll
    for (int j = 0; j < 4; ++j) {
      int ar = m0 + j * 64 + trow;
      if (ar > n_e - 1) ar = n_e - 1;
      aS[j] = A + (size_t)(o + ar) * KD + k0 + kx;
      bS[j] = Bex + (size_t)(j * 64 + trow) * KD;
    }

    f32x4 acc[8][4];
    #pragma unroll
    for (int m = 0; m < 8; ++m)
      #pragma unroll
      for (int n = 0; n < 4; ++n) acc[m][n] = (f32x4){0.f, 0.f, 0.f, 0.f};

    bf16x8 avL[8], avH[8], bvL[4], bvH[4];

    // ---- prologue: stage tile0 -> buf0, tile1 -> buf1 ----
    STG(aS[0], 0 + dstA);        STG(aS[2], 8192 + dstA);
    STG(aS[1], 4096 + dstA);     STG(aS[3], 12288 + dstA);
    STG(bS[0], 16384 + dstA);    STG(bS[1], 20480 + dstA);
    STG(bS[2], 24576 + dstA);    STG(bS[3], 28672 + dstA);
    STG(aS[0] + 64, 32768 + 0 + dstA);     STG(aS[2] + 64, 32768 + 8192 + dstA);
    STG(aS[1] + 64, 32768 + 4096 + dstA);  STG(aS[3] + 64, 32768 + 12288 + dstA);
    STG(bS[0] + 64, 32768 + 16384 + dstA); STG(bS[1] + 64, 32768 + 20480 + dstA);
    STG(bS[2] + 64, 32768 + 24576 + dstA); STG(bS[3] + 64, 32768 + 28672 + dstA);
    asm volatile("s_waitcnt vmcnt(8)");            // tile0 landed
    __builtin_amdgcn_s_barrier();
    __builtin_amdgcn_sched_barrier(0);
    // pre-read avL(0), bvL(0)
    {
      const int aA = aoff0, bA = boff0;
      DSR(avL[0], aA);        DSR(avL[1], aA ^ 64);
      DSR(avL[2], aA + 2048); DSR(avL[3], (aA + 2048) ^ 64);
      DSR(avL[4], aA + 4096); DSR(avL[5], (aA + 4096) ^ 64);
      DSR(avL[6], aA + 6144); DSR(avL[7], (aA + 6144) ^ 64);
      DSR(bvL[0], bA);        DSR(bvL[1], bA ^ 64);
      DSR(bvL[2], bA + 2048); DSR(bvL[3], (bA + 2048) ^ 64);
    }

    #pragma unroll 1
    for (int t = 0; t < NKT; ++t) {
      const int bb = (t & 1) << 16;          // byte offset of current buffer
      const int aA = aoff0 + bb;
      const int bA = boff0 + bb;
      const int cbu = (t & 1) * 32768;       // ushort base of current buffer
      const size_t ko = (size_t)(t + 2) * 64;
      const bool pf = (t + 2 < NKT);

      // ---- Q0: read avH(t); wait avL/bvL; stage A-low(t+2); MFMA mL x nL ----
      DSR(avH[0], aA + 8192);         DSR(avH[1], (aA + 8192) ^ 64);
      DSR(avH[2], aA + 10240);        DSR(avH[3], (aA + 10240) ^ 64);
      DSR(avH[4], aA + 12288);        DSR(avH[5], (aA + 12288) ^ 64);
      DSR(avH[6], aA + 14336);        DSR(avH[7], (aA + 14336) ^ 64);
      __builtin_amdgcn_s_barrier();
      asm volatile("s_waitcnt lgkmcnt(8)");
      __builtin_amdgcn_sched_barrier(0);
      if (pf) { STG(aS[0] + ko, cbu + 0 + dstA); STG(aS[2] + ko, cbu + 8192 + dstA); }
      __builtin_amdgcn_s_setprio(1);
      MQ(0, 0, avL, bvL);
      __builtin_amdgcn_s_setprio(0);
      __builtin_amdgcn_s_barrier();

      // ---- Q1: read bvH(t); wait avH; stage A-high(t+2); MFMA mH x nL ----
      DSR(bvH[0], bA + 4096);  DSR(bvH[1], (bA + 4096) ^ 64);
      DSR(bvH[2], bA + 6144);  DSR(bvH[3], (bA + 6144) ^ 64);
      __builtin_amdgcn_s_barrier();
      asm volatile("s_waitcnt lgkmcnt(4)");
      __builtin_amdgcn_sched_barrier(0);
      if (pf) { STG(aS[1] + ko, cbu + 4096 + dstA); STG(aS[3] + ko, cbu + 12288 + dstA); }
      __builtin_amdgcn_s_setprio(1);
      MQ(4, 0, avH, bvL);
      __builtin_amdgcn_s_setprio(0);
      __builtin_amdgcn_s_barrier();

      // ---- Q2: wait bvH; stage B(t+2); MFMA mL x nH ----
      __builtin_amdgcn_s_barrier();
      asm volatile("s_waitcnt lgkmcnt(0)");
      __builtin_amdgcn_sched_barrier(0);
      if (pf) {
        STG(bS[0] + ko, cbu + 16384 + dstA); STG(bS[1] + ko, cbu + 20480 + dstA);
        STG(bS[2] + ko, cbu + 24576 + dstA); STG(bS[3] + ko, cbu + 28672 + dstA);
      }
      __builtin_amdgcn_s_setprio(1);
      MQ(0, 2, avL, bvH);
      __builtin_amdgcn_s_setprio(0);
      __builtin_amdgcn_s_barrier();

      // ---- Q3: ensure tile t+1 staged; read avL/bvL(t+1); MFMA mH x nH ----
      if (pf) asm volatile("s_waitcnt vmcnt(8)");
      else    asm volatile("s_waitcnt vmcnt(0)");
      __builtin_amdgcn_s_barrier();
      __builtin_amdgcn_sched_barrier(0);
      if (t + 1 < NKT) {
        const int aN = aoff0 + (((t + 1) & 1) << 16);
        const int bN = boff0 + (((t + 1) & 1) << 16);
        DSR(avL[0], aN);        DSR(avL[1], aN ^ 64);
        DSR(avL[2], aN + 2048); DSR(avL[3], (aN + 2048) ^ 64);
        DSR(avL[4], aN + 4096); DSR(avL[5], (aN + 4096) ^ 64);
        DSR(avL[6], aN + 6144); DSR(avL[7], (aN + 6144) ^ 64);
        DSR(bvL[0], bN);        DSR(bvL[1], bN ^ 64);
        DSR(bvL[2], bN + 2048); DSR(bvL[3], (bN + 2048) ^ 64);
      }
      __builtin_amdgcn_s_setprio(1);
      MQ(4, 2, avH, bvH);
      __builtin_amdgcn_s_setprio(0);
      __builtin_amdgcn_s_barrier();
    }

    // ---- epilogue ----
    const int colBase = ni * 256 + wn * 64 + fr;      // + nf*16
    const int rBase = m0 + wm * 128 + q2 * 4;         // + mf*16 + jj
    float bb4[4];
    #pragma unroll
    for (int n = 0; n < 4; ++n) {
      if constexpr (EPI == 0)
        bb4[n] = bias[(size_t)e * NDIM + colBase + n * 16];
      else
        bb4[n] = (kh == 0) ? bias[(size_t)e * NDIM + colBase + n * 16] : 0.f;
    }

    if constexpr (EPI == 0) {
      #pragma unroll
      for (int m = 0; m < 8; ++m) {
        #pragma unroll
        for (int jj = 0; jj < 4; ++jj) {
          int r = rBase + m * 16 + jj;
          if (r < n_e) {
            ushort* hp = Hout + (size_t)(o + r) * NDIM + colBase;
            #pragma unroll
            for (int n = 0; n < 4; ++n)
              hp[n * 16] = f2bf(fmaxf(acc[m][n][jj] + bb4[n], 0.f));
          }
        }
      }
    } else {
      float* yk = Y + ((size_t)kh << 25);             // 16384*2048 = 1<<25
      #pragma unroll
      for (int m = 0; m < 8; ++m) {
        #pragma unroll
        for (int jj = 0; jj < 4; ++jj) {
          int r = rBase + m * 16 + jj;
          if (r < n_e) {
            float g = gate[o + r];
            float* yp = yk + (size_t)(o + r) * NDIM + colBase;
            #pragma unroll
            for (int n = 0; n < 4; ++n)
              yp[n * 16] = g * (acc[m][n][jj] + bb4[n]);
          }
        }
      }
    }
  }
#undef STG
}

// ---------------- combine: out[t] = sum over 2 slots x 2 K-halves ----------------
__global__ __launch_bounds__(256) void k_combine(
    const float* __restrict__ Y, const int* __restrict__ slt,
    float* __restrict__ out)
{
  const int t = blockIdx.x;
  const int c = threadIdx.x * 8;
  const int sA = slt[t * 2], sB = slt[t * 2 + 1];
  const float4* pA0 = (const float4*)(Y + (size_t)sA * DDIM + c);
  const float4* pB0 = (const float4*)(Y + (size_t)sB * DDIM + c);
  const float4* pA1 = (const float4*)(Y + ((size_t)1 << 25) + (size_t)sA * DDIM + c);
  const float4* pB1 = (const float4*)(Y + ((size_t)1 << 25) + (size_t)sB * DDIM + c);
  float4* op = (float4*)(out + (size_t)t * DDIM + c);
  #pragma unroll
  for (int j = 0; j < 2; ++j) {
    float4 a = pA0[j], b = pA1[j], cc = pB0[j], d = pB1[j];
    float4 r;
    r.x = a.x + b.x + cc.x + d.x;
    r.y = a.y + b.y + cc.y + d.y;
    r.z = a.z + b.z + cc.z + d.z;
    r.w = a.w + b.w + cc.w + d.w;
    op[j] = r;
  }
}

extern "C" void kernel_launch(void* const* d_in, const int* in_sizes, int n_in,
                              void* d_out, int out_size, void* d_ws, size_t ws_size,
                              hipStream_t stream) {
  const float* x   = (const float*)d_in[0];
  const float* eps = (const float*)d_in[1];
  const float* Wr  = (const float*)d_in[2];
  const float* br  = (const float*)d_in[3];
  const float* Wn  = (const float*)d_in[4];
  const float* bn  = (const float*)d_in[5];
  const float* W1  = (const float*)d_in[6];
  const float* b1  = (const float*)d_in[7];
  const float* W2  = (const float*)d_in[8];
  const float* b2  = (const float*)d_in[9];
  float* out = (float*)d_out;

  char* p = (char*)d_ws;
  size_t used = 0;
  auto alloc = [&](size_t bytes) -> void* {
    void* r = p + used;
    used += (bytes + 255) & ~(size_t)255;
    return r;
  };
  int*    cnt   = (int*)alloc(EEXP * 4);
  int*    off   = (int*)alloc((EEXP + 1) * 4);
  int*    tm1   = (int*)alloc(MAXT1 * 4);
  int*    tm2   = (int*)alloc(MAXT2 * 4);
  int*    ntl   = (int*)alloc(2 * 4);
  int*    tk_e  = (int*)alloc(2 * BT_TOK * 4);
  int*    tk_p  = (int*)alloc(2 * BT_TOK * 4);
  float*  tk_g  = (float*)alloc(2 * BT_TOK * 4);
  int*    slt   = (int*)alloc(2 * BT_TOK * 4);
  float*  gate  = (float*)alloc(2 * BT_TOK * 4);
  ushort* xg    = (ushort*)alloc((size_t)2 * BT_TOK * DDIM * 2);
  ushort* Wt1   = (ushort*)alloc((size_t)EEXP * HDIM * DDIM * 2);   // aliased as Y after GEMM1
  ushort* Wt2   = (ushort*)alloc((size_t)EEXP * HDIM * DDIM * 2);
  ushort* hbuf  = (ushort*)alloc((size_t)2 * BT_TOK * HDIM * 2);
  if (used > ws_size) return;
  float* Yf = (float*)Wt1;   // 2 * 16384 * 2048 * 4 B == 8*8192*2048*2 B

  hipMemsetAsync(cnt, 0, EEXP * 4, stream);

  k_router<<<BT_TOK / 4, 256, 0, stream>>>(x, eps, Wr, br, Wn, bn,
                                           cnt, tk_e, tk_p, tk_g);
  k_off<<<1, 64, 0, stream>>>(cnt, off, tm1, tm2, ntl);
  k_gather<<<2 * BT_TOK, 256, 0, stream>>>(x, off, tk_e, tk_p, tk_g, slt, gate, xg);

  {
    dim3 g1(HDIM / 64, DDIM / 64, EEXP);   // W1 [D][H] -> Wt1 [H][D]
    k_transpose<<<g1, 256, 0, stream>>>(W1, Wt1, DDIM, HDIM);
    dim3 g2(DDIM / 64, HDIM / 64, EEXP);   // W2 [H][D] -> Wt2 [D][H]
    k_transpose<<<g2, 256, 0, stream>>>(W2, Wt2, HDIM, DDIM);
  }

  k_gemm<DDIM, 1, 0, HDIM><<<256, 512, 0, stream>>>(xg, Wt1, b1, off, tm1, ntl,
                                                    gate, hbuf, Yf);
  k_gemm<HDIM, 2, 1, DDIM><<<256, 512, 0, stream>>>(hbuf, Wt2, b2, off, tm2, ntl + 1,
                                                    gate, hbuf, Yf);
  k_combine<<<BT_TOK, 256, 0, stream>>>(Yf, slt, out);
}

// Round 5
// 1735.757 us; speedup vs baseline: 2.2757x; 1.0334x over previous
//
#include <hip/hip_runtime.h>

#define BT_TOK 8192   // B*T
#define DDIM   2048
#define EEXP   8
#define HDIM   8192
#define MAXT1  72     // sum_e ceil(n_e/256) <= 64+8
#define MAXT2  144

typedef __bf16 bf16x8 __attribute__((ext_vector_type(8)));
typedef float  f32x4  __attribute__((ext_vector_type(4)));

__device__ inline ushort f2bf(float f) {
  unsigned u = __float_as_uint(f);
  u += 0x7FFFu + ((u >> 16) & 1u);   // RNE
  return (ushort)(u >> 16);
}

__device__ __forceinline__ void gl16(const ushort* g, ushort* l) {
  __builtin_amdgcn_global_load_lds(
      (const __attribute__((address_space(1))) void*)g,
      (__attribute__((address_space(3))) void*)l, 16, 0, 0);
}

// ---------------- router: 1 wave per token ----------------
__global__ __launch_bounds__(256) void k_router(
    const float* __restrict__ x, const float* __restrict__ eps,
    const float* __restrict__ Wr, const float* __restrict__ br,
    const float* __restrict__ Wn, const float* __restrict__ bn,
    int* __restrict__ cnt, int* __restrict__ tk_e, int* __restrict__ tk_p,
    float* __restrict__ tk_g)
{
  const int lane = threadIdx.x & 63;
  const int t = blockIdx.x * 4 + (threadIdx.x >> 6);
  const float* xr = x + (size_t)t * DDIM;
  float aL[8] = {0,0,0,0,0,0,0,0};
  float aN[8] = {0,0,0,0,0,0,0,0};
  for (int i = lane; i < DDIM; i += 64) {
    float xv = xr[i];
    const float4* wr4 = (const float4*)(Wr + (size_t)i * EEXP);
    const float4* wn4 = (const float4*)(Wn + (size_t)i * EEXP);
    float4 r0 = wr4[0], r1 = wr4[1];
    float4 n0 = wn4[0], n1 = wn4[1];
    aL[0] += xv * r0.x; aL[1] += xv * r0.y; aL[2] += xv * r0.z; aL[3] += xv * r0.w;
    aL[4] += xv * r1.x; aL[5] += xv * r1.y; aL[6] += xv * r1.z; aL[7] += xv * r1.w;
    aN[0] += xv * n0.x; aN[1] += xv * n0.y; aN[2] += xv * n0.z; aN[3] += xv * n0.w;
    aN[4] += xv * n1.x; aN[5] += xv * n1.y; aN[6] += xv * n1.z; aN[7] += xv * n1.w;
  }
  #pragma unroll
  for (int e = 0; e < 8; ++e) {
    float v = aL[e];
    #pragma unroll
    for (int s = 32; s; s >>= 1) v += __shfl_xor(v, s);
    aL[e] = v;
    float w = aN[e];
    #pragma unroll
    for (int s = 32; s; s >>= 1) w += __shfl_xor(w, s);
    aN[e] = w;
  }
  float nz[8];
  #pragma unroll
  for (int e = 0; e < 8; ++e) {
    float l = aL[e] + br[e];
    float z = aN[e] + bn[e];
    float sp = fmaxf(z, 0.f) + log1pf(expf(-fabsf(z)));   // stable softplus
    nz[e] = l + eps[(size_t)t * EEXP + e] * sp;
  }
  int e1 = 0; float v1 = nz[0];
  #pragma unroll
  for (int e = 1; e < 8; ++e) if (nz[e] > v1) { v1 = nz[e]; e1 = e; }
  int e2 = (e1 == 0) ? 1 : 0; float v2 = nz[e2];
  #pragma unroll
  for (int e = 0; e < 8; ++e) if (e != e1 && nz[e] > v2) { v2 = nz[e]; e2 = e; }
  float ex = expf(v2 - v1);
  float g1 = 1.f / (1.f + ex);
  float g2 = ex / (1.f + ex);
  if (lane == 0) {
    int p1 = atomicAdd(&cnt[e1], 1);
    int p2 = atomicAdd(&cnt[e2], 1);
    tk_e[t * 2 + 0] = e1; tk_p[t * 2 + 0] = p1; tk_g[t * 2 + 0] = g1;
    tk_e[t * 2 + 1] = e2; tk_p[t * 2 + 1] = p2; tk_g[t * 2 + 1] = g2;
  }
}

// ---------------- offsets + tile maps (pack = (e<<8)|(mi<<1)|kh) ----------------
__global__ void k_off(const int* __restrict__ cnt, int* __restrict__ off,
                      int* __restrict__ tm1, int* __restrict__ tm2,
                      int* __restrict__ ntl) {
  if (threadIdx.x == 0 && blockIdx.x == 0) {
    int a = 0, n1 = 0, n2 = 0;
    for (int e = 0; e < EEXP; ++e) {
      off[e] = a;
      int mt = (cnt[e] + 255) >> 8;
      for (int m = 0; m < mt; ++m) {
        tm1[n1++] = (e << 8) | (m << 1);
        tm2[n2++] = (e << 8) | (m << 1);
        tm2[n2++] = (e << 8) | (m << 1) | 1;
      }
      a += cnt[e];
    }
    off[EEXP] = a;
    ntl[0] = n1; ntl[1] = n2;
  }
}

// ---------------- slot fill + gather x -> bf16 xg ----------------
__global__ __launch_bounds__(256) void k_gather(
    const float* __restrict__ x, const int* __restrict__ off,
    const int* __restrict__ tk_e, const int* __restrict__ tk_p,
    const float* __restrict__ tk_g,
    int* __restrict__ slt, float* __restrict__ gate, ushort* __restrict__ xg)
{
  const int b = blockIdx.x;           // (t,k) pair
  const int t = b >> 1;
  const int e = tk_e[b];
  const int slot = off[e] + tk_p[b];
  if (threadIdx.x == 0) { slt[b] = slot; gate[slot] = tk_g[b]; }
  const float4* src = (const float4*)(x + (size_t)t * DDIM);
  ushort* dst = xg + (size_t)slot * DDIM;
  const int i = threadIdx.x;
  float4 a = src[i * 2 + 0];
  float4 c = src[i * 2 + 1];
  union { ushort u[8]; uint4 q; } pk;
  pk.u[0] = f2bf(a.x); pk.u[1] = f2bf(a.y); pk.u[2] = f2bf(a.z); pk.u[3] = f2bf(a.w);
  pk.u[4] = f2bf(c.x); pk.u[5] = f2bf(c.y); pk.u[6] = f2bf(c.z); pk.u[7] = f2bf(c.w);
  *(uint4*)(dst + (size_t)i * 8) = pk.q;
}

// ---------------- transpose + fp32->bf16:  W[e][R][C] -> Wt[e][C][R] ----------------
__global__ __launch_bounds__(256) void k_transpose(
    const float* __restrict__ W, ushort* __restrict__ Wt, int R, int C)
{
  const int e = blockIdx.z;
  const float* We = W + (size_t)e * R * C;
  ushort* Wte = Wt + (size_t)e * R * C;
  const int r0 = blockIdx.y * 64, c0 = blockIdx.x * 64;
  __shared__ float tile[64][65];
  const int tx = threadIdx.x & 15, ty = threadIdx.x >> 4;
  #pragma unroll
  for (int p = 0; p < 4; ++p) {
    float4 v = *(const float4*)(We + (size_t)(r0 + p * 16 + ty) * C + c0 + tx * 4);
    tile[p * 16 + ty][tx * 4 + 0] = v.x;
    tile[p * 16 + ty][tx * 4 + 1] = v.y;
    tile[p * 16 + ty][tx * 4 + 2] = v.z;
    tile[p * 16 + ty][tx * 4 + 3] = v.w;
  }
  __syncthreads();
  const int c = threadIdx.x >> 2, rb = (threadIdx.x & 3) * 16;
  union { ushort u[16]; uint4 q[2]; } pk;
  #pragma unroll
  for (int j = 0; j < 16; ++j) pk.u[j] = f2bf(tile[rb + j][c]);
  uint4* dst = (uint4*)(Wte + (size_t)(c0 + c) * R + r0 + rb);
  dst[0] = pk.q[0];
  dst[1] = pk.q[1];
}

// ---------------- grouped GEMM: 256x256 tile, BK=64, 8 waves (2Mx4N), persistent ----------------
// v5 schedule: 4 phases, ONE barrier each, LDS reads balanced 8/4/8/4.
//   Q0: DSR avH(t);            barA; lgkm(8); STG AL(t+2); MFMA mLxnL
//   Q1: DSR bvH(t);            barA; lgkm(4); STG AH(t+2); MFMA mHxnL
//   Q2: vmcnt(pf?4:0);         barA; lgkm(0); STG B(t+2);  MFMA mLxnH; DSR avL(t+1)
//   Q3:                        barA; DSR bvL(t+1);          MFMA mHxnH
// Region safety (one barrier between last read-issue and overwriting STG):
//   AL read Q2post/Q3(t-1) -> STG barA(Q0);  AH read Q0 -> STG barA(Q1);
//   B read Q1 -> STG barA(Q2).  t+1-staging visibility: vmcnt at Q2 + barA(Q2).
// MFMA within a quadrant ordered k-outer (dep distance 8, same per-acc order).

#define MFMA_(a, b, c) __builtin_amdgcn_mfma_f32_16x16x32_bf16(a, b, c, 0, 0, 0)
#define DSR(D, A) asm volatile("ds_read_b128 %0, %1" : "=v"(D) : "v"(A))
#define MQ(MB, NB, AV, BV) do {                                                  \
    _Pragma("unroll")                                                            \
    for (int i_ = 0; i_ < 4; ++i_) {                                             \
      acc[(MB)+i_][(NB)]   = MFMA_(AV[2*i_],   BV[0], acc[(MB)+i_][(NB)]);       \
      acc[(MB)+i_][(NB)+1] = MFMA_(AV[2*i_],   BV[2], acc[(MB)+i_][(NB)+1]);     \
    }                                                                            \
    _Pragma("unroll")                                                            \
    for (int i_ = 0; i_ < 4; ++i_) {                                             \
      acc[(MB)+i_][(NB)]   = MFMA_(AV[2*i_+1], BV[1], acc[(MB)+i_][(NB)]);       \
      acc[(MB)+i_][(NB)+1] = MFMA_(AV[2*i_+1], BV[3], acc[(MB)+i_][(NB)+1]);     \
    }                                                                            \
  } while (0)

template<int KD, int KSPLIT, int EPI, int NDIM>
__global__ __launch_bounds__(512, 2) void k_gemm(
    const ushort* __restrict__ A, const ushort* __restrict__ B,
    const float* __restrict__ bias, const int* __restrict__ off,
    const int* __restrict__ tileMap, const int* __restrict__ nT,
    const float* __restrict__ gate,
    ushort* __restrict__ Hout, float* __restrict__ Y)
{
  constexpr int KS = KD / KSPLIT;
  constexpr int NKT = KS / 64;
  constexpr int NTN = NDIM / 256;
  __shared__ ushort lds[65536];            // 128 KB
  const int TM = nT[0];
  const int T = TM * NTN;

  // bijective XCD chunking over flat tile ids (n-major: f = ni*TM + j)
  const int bid = blockIdx.x;
  const int xcd = bid & 7, sl = bid >> 3;
  const int qq = T >> 3, rr = T & 7;
  const int base = xcd * qq + (xcd < rr ? xcd : rr);
  const int csz = qq + (xcd < rr ? 1 : 0);

  const int tid = threadIdx.x;
  const int lane = tid & 63, wid = tid >> 6;
  const int wm = wid >> 2, wn = wid & 3;
  const int fr = lane & 15, q2 = lane >> 4;
  const unsigned lbase =
      (unsigned)(size_t)(__attribute__((address_space(3))) ushort*)lds;
  const int swz = (q2 ^ (fr & 7)) * 16;
  const int aoff0 = (int)lbase + wm * 16384 + fr * 128 + swz;           // + mf*2048, ^64 kk=1
  const int boff0 = (int)lbase + 32768 + wn * 8192 + fr * 128 + swz;    // + nf*2048
  const int trow = tid >> 3;                         // 0..63
  const int kx = ((tid & 7) ^ (trow & 7)) * 8;       // pre-swizzled global k-chunk
  const int dstA = tid * 8;                          // ushort idx within region

#define STG(SRC, DUS) gl16((SRC), &lds[DUS])

  for (int it = sl; it < csz; it += 32) {
    const int f = base + it;
    const int ni = (int)((unsigned)f / (unsigned)TM);
    const int pk = tileMap[f - ni * TM];
    const int e = pk >> 8, mi = (pk >> 1) & 127, kh = pk & 1;
    const int o = off[e], n_e = off[e + 1] - o;
    const int m0 = mi * 256;
    const int k0 = kh * KS;

    const ushort* Bex = B + (size_t)e * NDIM * KD + (size_t)ni * 256 * KD + k0 + kx;
    const ushort* aS[4]; const ushort* bS[4];
    #pragma unroll
    for (int j = 0; j < 4; ++j) {
      int ar = m0 + j * 64 + trow;
      if (ar > n_e - 1) ar = n_e - 1;
      aS[j] = A + (size_t)(o + ar) * KD + k0 + kx;
      bS[j] = Bex + (size_t)(j * 64 + trow) * KD;
    }

    f32x4 acc[8][4];
    #pragma unroll
    for (int m = 0; m < 8; ++m)
      #pragma unroll
      for (int n = 0; n < 4; ++n) acc[m][n] = (f32x4){0.f, 0.f, 0.f, 0.f};

    bf16x8 avL[8], avH[8], bvL[4], bvH[4];

    // ---- prologue: stage tile0 -> buf0, tile1 -> buf1 ----
    STG(aS[0], 0 + dstA);        STG(aS[2], 8192 + dstA);
    STG(aS[1], 4096 + dstA);     STG(aS[3], 12288 + dstA);
    STG(bS[0], 16384 + dstA);    STG(bS[1], 20480 + dstA);
    STG(bS[2], 24576 + dstA);    STG(bS[3], 28672 + dstA);
    STG(aS[0] + 64, 32768 + 0 + dstA);     STG(aS[2] + 64, 32768 + 8192 + dstA);
    STG(aS[1] + 64, 32768 + 4096 + dstA);  STG(aS[3] + 64, 32768 + 12288 + dstA);
    STG(bS[0] + 64, 32768 + 16384 + dstA); STG(bS[1] + 64, 32768 + 20480 + dstA);
    STG(bS[2] + 64, 32768 + 24576 + dstA); STG(bS[3] + 64, 32768 + 28672 + dstA);
    asm volatile("s_waitcnt vmcnt(8)");            // tile0 landed
    __builtin_amdgcn_s_barrier();
    __builtin_amdgcn_sched_barrier(0);
    // pre-read avL(0), bvL(0)
    {
      const int aA = aoff0, bA = boff0;
      DSR(avL[0], aA);        DSR(avL[1], aA ^ 64);
      DSR(avL[2], aA + 2048); DSR(avL[3], (aA + 2048) ^ 64);
      DSR(avL[4], aA + 4096); DSR(avL[5], (aA + 4096) ^ 64);
      DSR(avL[6], aA + 6144); DSR(avL[7], (aA + 6144) ^ 64);
      DSR(bvL[0], bA);        DSR(bvL[1], bA ^ 64);
      DSR(bvL[2], bA + 2048); DSR(bvL[3], (bA + 2048) ^ 64);
    }

    #pragma unroll 1
    for (int t = 0; t < NKT; ++t) {
      const int bb = (t & 1) << 16;          // byte offset of current buffer
      const int aA = aoff0 + bb;
      const int bA = boff0 + bb;
      const int nbB = ((t + 1) & 1) << 16;   // next-buffer byte offset
      const int aN = aoff0 + nbB;
      const int bN = boff0 + nbB;
      const int cbu = (t & 1) * 32768;       // ushort base of current buffer
      const size_t ko = (size_t)(t + 2) * 64;
      const bool pf = (t + 2 < NKT);
      const bool rd1 = (t + 1 < NKT);

      // ---- Q0: read avH(t); barA; wait avL/bvL; stage AL(t+2); MFMA mL x nL ----
      DSR(avH[0], aA + 8192);         DSR(avH[1], (aA + 8192) ^ 64);
      DSR(avH[2], aA + 10240);        DSR(avH[3], (aA + 10240) ^ 64);
      DSR(avH[4], aA + 12288);        DSR(avH[5], (aA + 12288) ^ 64);
      DSR(avH[6], aA + 14336);        DSR(avH[7], (aA + 14336) ^ 64);
      __builtin_amdgcn_s_barrier();
      asm volatile("s_waitcnt lgkmcnt(8)");
      __builtin_amdgcn_sched_barrier(0);
      if (pf) { STG(aS[0] + ko, cbu + 0 + dstA); STG(aS[2] + ko, cbu + 8192 + dstA); }
      __builtin_amdgcn_s_setprio(1);
      MQ(0, 0, avL, bvL);
      __builtin_amdgcn_s_setprio(0);

      // ---- Q1: read bvH(t); barA; wait avH; stage AH(t+2); MFMA mH x nL ----
      DSR(bvH[0], bA + 4096);  DSR(bvH[1], (bA + 4096) ^ 64);
      DSR(bvH[2], bA + 6144);  DSR(bvH[3], (bA + 6144) ^ 64);
      __builtin_amdgcn_s_barrier();
      asm volatile("s_waitcnt lgkmcnt(4)");
      __builtin_amdgcn_sched_barrier(0);
      if (pf) { STG(aS[1] + ko, cbu + 4096 + dstA); STG(aS[3] + ko, cbu + 12288 + dstA); }
      __builtin_amdgcn_s_setprio(1);
      MQ(4, 0, avH, bvL);
      __builtin_amdgcn_s_setprio(0);

      // ---- Q2: vmcnt (t+1 staged); barA; wait bvH; stage B(t+2); MFMA mL x nH;
      //          then read avL(t+1) from the other buffer ----
      if (pf) asm volatile("s_waitcnt vmcnt(4)");
      else    asm volatile("s_waitcnt vmcnt(0)");
      __builtin_amdgcn_s_barrier();
      asm volatile("s_waitcnt lgkmcnt(0)");
      __builtin_amdgcn_sched_barrier(0);
      if (pf) {
        STG(bS[0] + ko, cbu + 16384 + dstA); STG(bS[1] + ko, cbu + 20480 + dstA);
        STG(bS[2] + ko, cbu + 24576 + dstA); STG(bS[3] + ko, cbu + 28672 + dstA);
      }
      __builtin_amdgcn_s_setprio(1);
      MQ(0, 2, avL, bvH);
      __builtin_amdgcn_s_setprio(0);
      if (rd1) {
        DSR(avL[0], aN);        DSR(avL[1], aN ^ 64);
        DSR(avL[2], aN + 2048); DSR(avL[3], (aN + 2048) ^ 64);
        DSR(avL[4], aN + 4096); DSR(avL[5], (aN + 4096) ^ 64);
        DSR(avL[6], aN + 6144); DSR(avL[7], (aN + 6144) ^ 64);
      }

      // ---- Q3: barA; read bvL(t+1); MFMA mH x nH ----
      __builtin_amdgcn_s_barrier();
      __builtin_amdgcn_sched_barrier(0);
      if (rd1) {
        DSR(bvL[0], bN);        DSR(bvL[1], bN ^ 64);
        DSR(bvL[2], bN + 2048); DSR(bvL[3], (bN + 2048) ^ 64);
      }
      __builtin_amdgcn_s_setprio(1);
      MQ(4, 2, avH, bvH);
      __builtin_amdgcn_s_setprio(0);
    }

    // ---- epilogue ----
    asm volatile("s_waitcnt vmcnt(0)");
    const int colBase = ni * 256 + wn * 64 + fr;      // + nf*16
    const int rBase = m0 + wm * 128 + q2 * 4;         // + mf*16 + jj
    float bb4[4];
    #pragma unroll
    for (int n = 0; n < 4; ++n) {
      if constexpr (EPI == 0)
        bb4[n] = bias[(size_t)e * NDIM + colBase + n * 16];
      else
        bb4[n] = (kh == 0) ? bias[(size_t)e * NDIM + colBase + n * 16] : 0.f;
    }

    if constexpr (EPI == 0) {
      #pragma unroll
      for (int m = 0; m < 8; ++m) {
        #pragma unroll
        for (int jj = 0; jj < 4; ++jj) {
          int r = rBase + m * 16 + jj;
          if (r < n_e) {
            ushort* hp = Hout + (size_t)(o + r) * NDIM + colBase;
            #pragma unroll
            for (int n = 0; n < 4; ++n)
              hp[n * 16] = f2bf(fmaxf(acc[m][n][jj] + bb4[n], 0.f));
          }
        }
      }
    } else {
      float* yk = Y + ((size_t)kh << 25);             // 16384*2048 = 1<<25
      #pragma unroll
      for (int m = 0; m < 8; ++m) {
        #pragma unroll
        for (int jj = 0; jj < 4; ++jj) {
          int r = rBase + m * 16 + jj;
          if (r < n_e) {
            float g = gate[o + r];
            float* yp = yk + (size_t)(o + r) * NDIM + colBase;
            #pragma unroll
            for (int n = 0; n < 4; ++n)
              yp[n * 16] = g * (acc[m][n][jj] + bb4[n]);
          }
        }
      }
    }
  }
#undef STG
}

// ---------------- combine: out[t] = sum over 2 slots x 2 K-halves ----------------
__global__ __launch_bounds__(256) void k_combine(
    const float* __restrict__ Y, const int* __restrict__ slt,
    float* __restrict__ out)
{
  const int t = blockIdx.x;
  const int c = threadIdx.x * 8;
  const int sA = slt[t * 2], sB = slt[t * 2 + 1];
  const float4* pA0 = (const float4*)(Y + (size_t)sA * DDIM + c);
  const float4* pB0 = (const float4*)(Y + (size_t)sB * DDIM + c);
  const float4* pA1 = (const float4*)(Y + ((size_t)1 << 25) + (size_t)sA * DDIM + c);
  const float4* pB1 = (const float4*)(Y + ((size_t)1 << 25) + (size_t)sB * DDIM + c);
  float4* op = (float4*)(out + (size_t)t * DDIM + c);
  #pragma unroll
  for (int j = 0; j < 2; ++j) {
    float4 a = pA0[j], b = pA1[j], cc = pB0[j], d = pB1[j];
    float4 r;
    r.x = a.x + b.x + cc.x + d.x;
    r.y = a.y + b.y + cc.y + d.y;
    r.z = a.z + b.z + cc.z + d.z;
    r.w = a.w + b.w + cc.w + d.w;
    op[j] = r;
  }
}

extern "C" void kernel_launch(void* const* d_in, const int* in_sizes, int n_in,
                              void* d_out, int out_size, void* d_ws, size_t ws_size,
                              hipStream_t stream) {
  const float* x   = (const float*)d_in[0];
  const float* eps = (const float*)d_in[1];
  const float* Wr  = (const float*)d_in[2];
  const float* br  = (const float*)d_in[3];
  const float* Wn  = (const float*)d_in[4];
  const float* bn  = (const float*)d_in[5];
  const float* W1  = (const float*)d_in[6];
  const float* b1  = (const float*)d_in[7];
  const float* W2  = (const float*)d_in[8];
  const float* b2  = (const float*)d_in[9];
  float* out = (float*)d_out;

  char* p = (char*)d_ws;
  size_t used = 0;
  auto alloc = [&](size_t bytes) -> void* {
    void* r = p + used;
    used += (bytes + 255) & ~(size_t)255;
    return r;
  };
  int*    cnt   = (int*)alloc(EEXP * 4);
  int*    off   = (int*)alloc((EEXP + 1) * 4);
  int*    tm1   = (int*)alloc(MAXT1 * 4);
  int*    tm2   = (int*)alloc(MAXT2 * 4);
  int*    ntl   = (int*)alloc(2 * 4);
  int*    tk_e  = (int*)alloc(2 * BT_TOK * 4);
  int*    tk_p  = (int*)alloc(2 * BT_TOK * 4);
  float*  tk_g  = (float*)alloc(2 * BT_TOK * 4);
  int*    slt   = (int*)alloc(2 * BT_TOK * 4);
  float*  gate  = (float*)alloc(2 * BT_TOK * 4);
  ushort* xg    = (ushort*)alloc((size_t)2 * BT_TOK * DDIM * 2);
  ushort* Wt1   = (ushort*)alloc((size_t)EEXP * HDIM * DDIM * 2);   // aliased as Y after GEMM1
  ushort* Wt2   = (ushort*)alloc((size_t)EEXP * HDIM * DDIM * 2);
  ushort* hbuf  = (ushort*)alloc((size_t)2 * BT_TOK * HDIM * 2);
  if (used > ws_size) return;
  float* Yf = (float*)Wt1;   // 2 * 16384 * 2048 * 4 B == 8*8192*2048*2 B

  hipMemsetAsync(cnt, 0, EEXP * 4, stream);

  k_router<<<BT_TOK / 4, 256, 0, stream>>>(x, eps, Wr, br, Wn, bn,
                                           cnt, tk_e, tk_p, tk_g);
  k_off<<<1, 64, 0, stream>>>(cnt, off, tm1, tm2, ntl);
  k_gather<<<2 * BT_TOK, 256, 0, stream>>>(x, off, tk_e, tk_p, tk_g, slt, gate, xg);

  {
    dim3 g1(HDIM / 64, DDIM / 64, EEXP);   // W1 [D][H] -> Wt1 [H][D]
    k_transpose<<<g1, 256, 0, stream>>>(W1, Wt1, DDIM, HDIM);
    dim3 g2(DDIM / 64, HDIM / 64, EEXP);   // W2 [H][D] -> Wt2 [D][H]
    k_transpose<<<g2, 256, 0, stream>>>(W2, Wt2, HDIM, DDIM);
  }

  k_gemm<DDIM, 1, 0, HDIM><<<256, 512, 0, stream>>>(xg, Wt1, b1, off, tm1, ntl,
                                                    gate, hbuf, Yf);
  k_gemm<HDIM, 2, 1, DDIM><<<256, 512, 0, stream>>>(hbuf, Wt2, b2, off, tm2, ntl + 1,
                                                    gate, hbuf, Yf);
  k_combine<<<BT_TOK, 256, 0, stream>>>(Yf, slt, out);
}